// Round 1
// baseline (591.717 us; speedup 1.0000x reference)
//
#include <hip/hip_runtime.h>
#include <hip/hip_bf16.h>
#include <stdint.h>

#define AS1 __attribute__((address_space(1)))
#define AS3 __attribute__((address_space(3)))

typedef __bf16 bf16_t;
typedef __bf16 bf16x8 __attribute__((ext_vector_type(8)));
typedef float f32x4 __attribute__((ext_vector_type(4)));

static constexpr int Bsz = 2, T = 2048, Cdim = 2048, NH = 16, DH = 128;
static constexpr int M  = Bsz * T;    // 4096
static constexpr int N1 = 3 * Cdim;   // 6144
static constexpr int K1 = Cdim;       // 2048

__device__ __forceinline__ unsigned short f2bf(float f) {
  unsigned u = __float_as_uint(f);
  u += 0x7fffu + ((u >> 16) & 1u);
  return (unsigned short)(u >> 16);
}

__device__ __forceinline__ void gload_lds16(const bf16_t* g, void* l) {
  __builtin_amdgcn_global_load_lds((AS1 const void*)g, (AS3 void*)l, 16, 0, 0);
}

// ---------------- fp32 -> bf16 elementwise convert (vec4) ----------------
__global__ void cvt_kernel(const float* __restrict__ in, unsigned short* __restrict__ out, int n) {
  int i = (blockIdx.x * blockDim.x + threadIdx.x) * 4;
  if (i >= n) return;
  float4 v = *(const float4*)(in + i);
  ushort4 o;
  o.x = f2bf(v.x); o.y = f2bf(v.y); o.z = f2bf(v.z); o.w = f2bf(v.w);
  *(ushort4*)(out + i) = o;
}

// ---------------- fp32 (KxN) -> bf16 transpose (NxK) ----------------
__global__ void transpose_cvt_kernel(const float* __restrict__ in, unsigned short* __restrict__ out,
                                     int K, int N) {
  __shared__ float tile[32][33];
  int n0 = blockIdx.x * 32, k0 = blockIdx.y * 32;
  int tx = threadIdx.x, ty = threadIdx.y;  // 32 x 8
#pragma unroll
  for (int i = 0; i < 32; i += 8)
    tile[ty + i][tx] = in[(size_t)(k0 + ty + i) * N + n0 + tx];
  __syncthreads();
#pragma unroll
  for (int i = 0; i < 32; i += 8)
    out[(size_t)(n0 + ty + i) * K + k0 + tx] = f2bf(tile[tx][ty + i]);
}

// ---------------- bf16 GEMM: A (MxK) * BT (NxK, pre-transposed) ----------------
// 128x128 tile, BK=32, 4 waves (each 64x64), 16x16x32 MFMA, global_load_lds staging.
template <int OUT_BF16>
__global__ __launch_bounds__(256) void gemm_bt(const bf16_t* __restrict__ A,
                                               const bf16_t* __restrict__ BT,
                                               void* __restrict__ Cp,
                                               int Mm, int Nn, int Kk) {
  constexpr int BM = 128, BN = 128, BK = 32;
  __shared__ __align__(16) bf16_t As[BM * BK];
  __shared__ __align__(16) bf16_t Bs[BN * BK];
  const int tid = threadIdx.x;
  const int wid = tid >> 6, lane = tid & 63;
  const int m0 = blockIdx.y * BM, n0 = blockIdx.x * BN;
  const int wr = wid >> 1, wc = wid & 1;
  const int lq = lane & 15, lk = lane >> 4;

  f32x4 acc[4][4] = {};

  // staging: tile 8192 B total; wave covers 2048 B = 2 issues x (64 lanes * 16 B)
  const int e0 = wid * 1024 + lane * 8;  // element index within [128][32] tile (issue 0)
  const int r0 = e0 >> 5, c0 = e0 & 31;
  const bf16_t* Ag0 = A + (size_t)(m0 + r0) * Kk + c0;
  const bf16_t* Ag1 = A + (size_t)(m0 + r0 + 16) * Kk + c0;
  const bf16_t* Bg0 = BT + (size_t)(n0 + r0) * Kk + c0;
  const bf16_t* Bg1 = BT + (size_t)(n0 + r0 + 16) * Kk + c0;
  bf16_t* Asl0 = As + wid * 1024;
  bf16_t* Asl1 = As + wid * 1024 + 512;
  bf16_t* Bsl0 = Bs + wid * 1024;
  bf16_t* Bsl1 = Bs + wid * 1024 + 512;

  const int nk = Kk >> 5;
  for (int kt = 0; kt < nk; ++kt) {
    const int ko = kt << 5;
    __syncthreads();
    gload_lds16(Ag0 + ko, Asl0);
    gload_lds16(Ag1 + ko, Asl1);
    gload_lds16(Bg0 + ko, Bsl0);
    gload_lds16(Bg1 + ko, Bsl1);
    __syncthreads();
    bf16x8 af[4], bfr[4];
#pragma unroll
    for (int m = 0; m < 4; ++m)
      af[m] = *(const bf16x8*)&As[(wr * 64 + m * 16 + lq) * 32 + lk * 8];
#pragma unroll
    for (int n = 0; n < 4; ++n)
      bfr[n] = *(const bf16x8*)&Bs[(wc * 64 + n * 16 + lq) * 32 + lk * 8];
#pragma unroll
    for (int m = 0; m < 4; ++m)
#pragma unroll
      for (int n = 0; n < 4; ++n)
        acc[m][n] = __builtin_amdgcn_mfma_f32_16x16x32_bf16(af[m], bfr[n], acc[m][n], 0, 0, 0);
  }

#pragma unroll
  for (int m = 0; m < 4; ++m)
#pragma unroll
    for (int n = 0; n < 4; ++n)
#pragma unroll
      for (int r = 0; r < 4; ++r) {
        int row = m0 + wr * 64 + m * 16 + lk * 4 + r;
        int col = n0 + wc * 64 + n * 16 + lq;
        if (OUT_BF16)
          ((unsigned short*)Cp)[(size_t)row * Nn + col] = f2bf(acc[m][n][r]);
        else
          ((float*)Cp)[(size_t)row * Nn + col] = acc[m][n][r];
      }
}

// ---------------- causal flash attention ----------------
// grid: (T/64, B*H). block: 256 (4 waves). wave w handles q rows [qtile*64+w*16, +16).
__global__ __launch_bounds__(256) void attn_kernel(const bf16_t* __restrict__ qkv,
                                                   unsigned short* __restrict__ y) {
  constexpr int KVBLK = 64;
  __shared__ __align__(16) bf16_t Ks[KVBLK * DH];   // [kv][d], XOR-swizzled
  __shared__ __align__(16) bf16_t Vt[DH * KVBLK];   // [d][kv], XOR-swizzled
  __shared__ __align__(16) bf16_t Ps[4][16][72];    // per-wave P, padded rows
  const int tid = threadIdx.x;
  const int wid = tid >> 6, lane = tid & 63;
  const int lq = lane & 15, lk = lane >> 4;
  const int qtile = blockIdx.x;
  const int bh = blockIdx.y;
  const int b = bh >> 4, h = bh & 15;
  const float scale = 0.08838834764831845f;  // 1/sqrt(128)

  const size_t rowbase = (size_t)(b * T) * N1;
  const int qlo = qtile * KVBLK + wid * 16;

  // Q fragments (held in registers for whole kernel)
  bf16x8 qf[4];
  {
    const bf16_t* Qg = qkv + rowbase + (size_t)(qlo + lq) * N1 + h * DH;
#pragma unroll
    for (int kk = 0; kk < 4; ++kk) qf[kk] = *(const bf16x8*)(Qg + kk * 32 + lk * 8);
  }

  f32x4 oacc[8] = {};
  float mrow[4] = {-1e30f, -1e30f, -1e30f, -1e30f};
  float lrow[4] = {0.f, 0.f, 0.f, 0.f};

  const int ntiles = qtile + 1;
  for (int t = 0; t < ntiles; ++t) {
    const int kv0 = t * KVBLK;
    __syncthreads();
    // stage K: global_load_lds, linear LDS dest + pre-swizzled global source
    {
      const bf16_t* Kg = qkv + rowbase + (size_t)kv0 * N1 + Cdim + h * DH;
#pragma unroll
      for (int i = 0; i < 4; ++i) {
        int p = wid * 4096 + i * 1024 + lane * 16;  // byte offset in 16KB tile
        int r = p >> 8;                             // kv row (256B rows)
        int csw = (p & 255) ^ ((r & 7) << 4);       // inverse-swizzled source col
        gload_lds16(Kg + (size_t)r * N1 + (csw >> 1), (char*)Ks + (wid * 4096 + i * 1024));
      }
    }
    // stage V transposed into Vt[d][kv] (scalar swizzled writes)
    {
      const bf16_t* Vg = qkv + rowbase + (size_t)kv0 * N1 + 2 * Cdim + h * DH;
#pragma unroll
      for (int i = 0; i < 4; ++i) {
        int gc = i * 256 + tid;
        int kv = gc >> 4;
        int d0 = (gc & 15) * 8;
        bf16x8 v = *(const bf16x8*)(Vg + (size_t)kv * N1 + d0);
#pragma unroll
        for (int j = 0; j < 8; ++j) {
          int o = ((d0 + j) * KVBLK + kv) * 2;
          o ^= (j << 4);  // (d&7)==j since d0%8==0
          *(bf16_t*)((char*)Vt + o) = v[j];
        }
      }
    }
    __syncthreads();

    if (kv0 <= qlo + 15) {
      // S = Q K^T  (A=Q frag, B=K row read, swizzled)
      f32x4 sacc[4] = {};
#pragma unroll
      for (int nf = 0; nf < 4; ++nf) {
        int r = nf * 16 + lq;
        int sw = (r & 7) << 4;
#pragma unroll
        for (int kk = 0; kk < 4; ++kk) {
          bf16x8 kf = *(const bf16x8*)((const char*)Ks + r * 256 + ((64 * kk + 16 * lk) ^ sw));
          sacc[nf] = __builtin_amdgcn_mfma_f32_16x16x32_bf16(qf[kk], kf, sacc[nf], 0, 0, 0);
        }
      }
      // online softmax
      float sv[4][4];
      float tm[4] = {-1e30f, -1e30f, -1e30f, -1e30f};
#pragma unroll
      for (int nf = 0; nf < 4; ++nf) {
        int kv = kv0 + nf * 16 + lq;
#pragma unroll
        for (int r = 0; r < 4; ++r) {
          int q = qlo + lk * 4 + r;
          float s = sacc[nf][r] * scale;
          if (kv > q) s = -1e30f;
          sv[nf][r] = s;
          tm[r] = fmaxf(tm[r], s);
        }
      }
#pragma unroll
      for (int r = 0; r < 4; ++r) {
        tm[r] = fmaxf(tm[r], __shfl_xor(tm[r], 1));
        tm[r] = fmaxf(tm[r], __shfl_xor(tm[r], 2));
        tm[r] = fmaxf(tm[r], __shfl_xor(tm[r], 4));
        tm[r] = fmaxf(tm[r], __shfl_xor(tm[r], 8));
      }
      float osc[4];
#pragma unroll
      for (int r = 0; r < 4; ++r) {
        float mn = fmaxf(mrow[r], tm[r]);
        osc[r] = __expf(mrow[r] - mn);
        mrow[r] = mn;
        lrow[r] *= osc[r];
      }
#pragma unroll
      for (int d = 0; d < 8; ++d)
#pragma unroll
        for (int r = 0; r < 4; ++r) oacc[d][r] *= osc[r];
      float rs[4] = {0.f, 0.f, 0.f, 0.f};
#pragma unroll
      for (int nf = 0; nf < 4; ++nf)
#pragma unroll
        for (int r = 0; r < 4; ++r) {
          float p = __expf(sv[nf][r] - mrow[r]);
          rs[r] += p;
          Ps[wid][lk * 4 + r][nf * 16 + lq] = (bf16_t)p;
        }
#pragma unroll
      for (int r = 0; r < 4; ++r) {
        rs[r] += __shfl_xor(rs[r], 1);
        rs[r] += __shfl_xor(rs[r], 2);
        rs[r] += __shfl_xor(rs[r], 4);
        rs[r] += __shfl_xor(rs[r], 8);
        lrow[r] += rs[r];
      }
      // O += P V   (A=P from LDS, B=Vt swizzled read)
#pragma unroll
      for (int s = 0; s < 2; ++s) {
        bf16x8 pa = *(const bf16x8*)&Ps[wid][lq][s * 32 + lk * 8];
#pragma unroll
        for (int df = 0; df < 8; ++df) {
          int d = df * 16 + lq;
          int o = d * 128 + (((s * 32 + lk * 8) * 2) ^ ((d & 7) << 4));
          bf16x8 vb = *(const bf16x8*)((const char*)Vt + o);
          oacc[df] = __builtin_amdgcn_mfma_f32_16x16x32_bf16(pa, vb, oacc[df], 0, 0, 0);
        }
      }
    }
  }

#pragma unroll
  for (int r = 0; r < 4; ++r) {
    float inv = 1.0f / lrow[r];
    int q = qlo + lk * 4 + r;
    unsigned short* yr = y + (size_t)(b * T + q) * Cdim + h * DH;
#pragma unroll
    for (int df = 0; df < 8; ++df) yr[df * 16 + lq] = f2bf(oacc[df][r] * inv);
  }
}

extern "C" void kernel_launch(void* const* d_in, const int* in_sizes, int n_in,
                              void* d_out, int out_size, void* d_ws, size_t ws_size,
                              hipStream_t stream) {
  const float* x  = (const float*)d_in[0];
  const float* Wa = (const float*)d_in[1];
  const float* Wp = (const float*)d_in[2];
  float* out = (float*)d_out;
  char* ws = (char*)d_ws;

  // workspace layout (bytes): total 117,440,512
  size_t o0 = 0;                            // xb   : M*K1 bf16 (16 MB)
  size_t o1 = o0 + (size_t)M * K1 * 2;      // WaT  : N1*K1 bf16 (24 MB)
  size_t o2 = o1 + (size_t)N1 * K1 * 2;     // qkv  : M*N1 bf16 (48 MB)
  size_t o3 = o2 + (size_t)M * N1 * 2;      // yb   : M*C bf16 (16 MB)
  size_t o4 = o3 + (size_t)M * Cdim * 2;    // WpT  : C*C bf16 (8 MB)

  unsigned short* xb   = (unsigned short*)(ws + o0);
  unsigned short* WaT  = (unsigned short*)(ws + o1);
  unsigned short* qkvb = (unsigned short*)(ws + o2);
  unsigned short* yb   = (unsigned short*)(ws + o3);
  unsigned short* WpT  = (unsigned short*)(ws + o4);

  cvt_kernel<<<dim3((M * K1 / 4 + 255) / 256), dim3(256), 0, stream>>>(x, xb, M * K1);
  transpose_cvt_kernel<<<dim3(N1 / 32, K1 / 32), dim3(32, 8), 0, stream>>>(Wa, WaT, K1, N1);
  transpose_cvt_kernel<<<dim3(Cdim / 32, Cdim / 32), dim3(32, 8), 0, stream>>>(Wp, WpT, Cdim, Cdim);

  gemm_bt<1><<<dim3(N1 / 128, M / 128), dim3(256), 0, stream>>>(
      (const bf16_t*)xb, (const bf16_t*)WaT, (void*)qkvb, M, N1, K1);

  attn_kernel<<<dim3(T / 64, Bsz * NH), dim3(256), 0, stream>>>(
      (const bf16_t*)qkvb, yb);

  gemm_bt<0><<<dim3(Cdim / 128, M / 128), dim3(256), 0, stream>>>(
      (const bf16_t*)yb, (const bf16_t*)WpT, (void*)out, M, Cdim, K1);
}

// Round 2
// 338.678 us; speedup vs baseline: 1.7471x; 1.7471x over previous
//
#include <hip/hip_runtime.h>
#include <hip/hip_bf16.h>
#include <stdint.h>

#define AS1 __attribute__((address_space(1)))
#define AS3 __attribute__((address_space(3)))

typedef __bf16 bf16_t;
typedef __bf16 bf16x8 __attribute__((ext_vector_type(8)));
typedef float f32x4 __attribute__((ext_vector_type(4)));

static constexpr int Bsz = 2, T = 2048, Cdim = 2048, NH = 16, DH = 128;
static constexpr int M  = Bsz * T;    // 4096
static constexpr int N1 = 3 * Cdim;   // 6144
static constexpr int K1 = Cdim;       // 2048

__device__ __forceinline__ unsigned short f2bf(float f) {
  unsigned u = __float_as_uint(f);
  u += 0x7fffu + ((u >> 16) & 1u);
  return (unsigned short)(u >> 16);
}

__device__ __forceinline__ void gload_lds16(const bf16_t* g, void* l) {
  __builtin_amdgcn_global_load_lds((AS1 const void*)g, (AS3 void*)l, 16, 0, 0);
}

// ---------------- fp32 -> bf16 elementwise convert (vec4) ----------------
__global__ void cvt_kernel(const float* __restrict__ in, unsigned short* __restrict__ out, int n) {
  int i = (blockIdx.x * blockDim.x + threadIdx.x) * 4;
  if (i >= n) return;
  float4 v = *(const float4*)(in + i);
  ushort4 o;
  o.x = f2bf(v.x); o.y = f2bf(v.y); o.z = f2bf(v.z); o.w = f2bf(v.w);
  *(ushort4*)(out + i) = o;
}

// ---------------- fp32 (KxN) -> bf16 transpose (NxK) ----------------
__global__ void transpose_cvt_kernel(const float* __restrict__ in, unsigned short* __restrict__ out,
                                     int K, int N) {
  __shared__ float tile[32][33];
  int n0 = blockIdx.x * 32, k0 = blockIdx.y * 32;
  int tx = threadIdx.x, ty = threadIdx.y;  // 32 x 8
#pragma unroll
  for (int i = 0; i < 32; i += 8)
    tile[ty + i][tx] = in[(size_t)(k0 + ty + i) * N + n0 + tx];
  __syncthreads();
#pragma unroll
  for (int i = 0; i < 32; i += 8)
    out[(size_t)(n0 + ty + i) * K + k0 + tx] = f2bf(tile[tx][ty + i]);
}

// ---------------- bf16 (T x DH slice of qkv V) -> bf16 Vt[bh][d][t] ----------------
__global__ void vtrans_kernel(const unsigned short* __restrict__ qkv, unsigned short* __restrict__ vt) {
  __shared__ unsigned short tile[32][33];
  int t0 = blockIdx.x * 32, d0 = blockIdx.y * 32, bh = blockIdx.z;
  int b = bh >> 4, h = bh & 15;
  int tx = threadIdx.x, ty = threadIdx.y;  // 32 x 8
  const unsigned short* src = qkv + (size_t)(b * T) * N1 + 2 * Cdim + h * DH;
#pragma unroll
  for (int i = 0; i < 32; i += 8)
    tile[ty + i][tx] = src[(size_t)(t0 + ty + i) * N1 + d0 + tx];
  __syncthreads();
  unsigned short* dst = vt + ((size_t)bh * DH + d0) * T + t0;
#pragma unroll
  for (int i = 0; i < 32; i += 8)
    dst[(size_t)(ty + i) * T + tx] = tile[tx][ty + i];
}

// ---------------- bf16 GEMM: A (MxK) * BT (NxK, pre-transposed) ----------------
template <int OUT_BF16>
__global__ __launch_bounds__(256) void gemm_bt(const bf16_t* __restrict__ A,
                                               const bf16_t* __restrict__ BT,
                                               void* __restrict__ Cp,
                                               int Mm, int Nn, int Kk) {
  constexpr int BM = 128, BN = 128, BK = 32;
  __shared__ __align__(16) bf16_t As[BM * BK];
  __shared__ __align__(16) bf16_t Bs[BN * BK];
  const int tid = threadIdx.x;
  const int wid = tid >> 6, lane = tid & 63;
  const int m0 = blockIdx.y * BM, n0 = blockIdx.x * BN;
  const int wr = wid >> 1, wc = wid & 1;
  const int lq = lane & 15, lk = lane >> 4;

  f32x4 acc[4][4] = {};

  const int e0 = wid * 1024 + lane * 8;
  const int r0 = e0 >> 5, c0 = e0 & 31;
  const bf16_t* Ag0 = A + (size_t)(m0 + r0) * Kk + c0;
  const bf16_t* Ag1 = A + (size_t)(m0 + r0 + 16) * Kk + c0;
  const bf16_t* Bg0 = BT + (size_t)(n0 + r0) * Kk + c0;
  const bf16_t* Bg1 = BT + (size_t)(n0 + r0 + 16) * Kk + c0;
  bf16_t* Asl0 = As + wid * 1024;
  bf16_t* Asl1 = As + wid * 1024 + 512;
  bf16_t* Bsl0 = Bs + wid * 1024;
  bf16_t* Bsl1 = Bs + wid * 1024 + 512;

  const int nk = Kk >> 5;
  for (int kt = 0; kt < nk; ++kt) {
    const int ko = kt << 5;
    __syncthreads();
    gload_lds16(Ag0 + ko, Asl0);
    gload_lds16(Ag1 + ko, Asl1);
    gload_lds16(Bg0 + ko, Bsl0);
    gload_lds16(Bg1 + ko, Bsl1);
    __syncthreads();
    bf16x8 af[4], bfr[4];
#pragma unroll
    for (int m = 0; m < 4; ++m)
      af[m] = *(const bf16x8*)&As[(wr * 64 + m * 16 + lq) * 32 + lk * 8];
#pragma unroll
    for (int n = 0; n < 4; ++n)
      bfr[n] = *(const bf16x8*)&Bs[(wc * 64 + n * 16 + lq) * 32 + lk * 8];
#pragma unroll
    for (int m = 0; m < 4; ++m)
#pragma unroll
      for (int n = 0; n < 4; ++n)
        acc[m][n] = __builtin_amdgcn_mfma_f32_16x16x32_bf16(af[m], bfr[n], acc[m][n], 0, 0, 0);
  }

#pragma unroll
  for (int m = 0; m < 4; ++m)
#pragma unroll
    for (int n = 0; n < 4; ++n)
#pragma unroll
      for (int r = 0; r < 4; ++r) {
        int row = m0 + wr * 64 + m * 16 + lk * 4 + r;
        int col = n0 + wc * 64 + n * 16 + lq;
        if (OUT_BF16)
          ((unsigned short*)Cp)[(size_t)row * Nn + col] = f2bf(acc[m][n][r]);
        else
          ((float*)Cp)[(size_t)row * Nn + col] = acc[m][n][r];
      }
}

// ---------------- causal flash attention, balanced-pair blocks ----------------
// One 4-wave block owns q-tiles {j, 31-j} of 64 rows each; wave w handles 16 rows of each.
// K and Vt (pre-transposed global) staged via global_load_lds with XOR-swizzle.
__device__ __forceinline__ void attn_process(
    const bf16_t* __restrict__ Ks, const bf16_t* __restrict__ Vs, bf16_t* __restrict__ Psw,
    const bf16x8* qf, f32x4* oacc, float* mrow, float* lrow,
    int qlo, int kv0, int lq, int lk, float scale) {
  // S = Q K^T
  f32x4 sacc[4] = {};
#pragma unroll
  for (int nf = 0; nf < 4; ++nf) {
    int r = nf * 16 + lq;
    int sw = (r & 7) << 4;
#pragma unroll
    for (int kk = 0; kk < 4; ++kk) {
      bf16x8 kf = *(const bf16x8*)((const char*)Ks + r * 256 + ((64 * kk + 16 * lk) ^ sw));
      sacc[nf] = __builtin_amdgcn_mfma_f32_16x16x32_bf16(qf[kk], kf, sacc[nf], 0, 0, 0);
    }
  }
  // online softmax
  float sv[4][4];
  float tm[4] = {-1e30f, -1e30f, -1e30f, -1e30f};
#pragma unroll
  for (int nf = 0; nf < 4; ++nf) {
    int kv = kv0 + nf * 16 + lq;
#pragma unroll
    for (int r = 0; r < 4; ++r) {
      int q = qlo + lk * 4 + r;
      float s = sacc[nf][r] * scale;
      if (kv > q) s = -1e30f;
      sv[nf][r] = s;
      tm[r] = fmaxf(tm[r], s);
    }
  }
#pragma unroll
  for (int r = 0; r < 4; ++r) {
    tm[r] = fmaxf(tm[r], __shfl_xor(tm[r], 1));
    tm[r] = fmaxf(tm[r], __shfl_xor(tm[r], 2));
    tm[r] = fmaxf(tm[r], __shfl_xor(tm[r], 4));
    tm[r] = fmaxf(tm[r], __shfl_xor(tm[r], 8));
  }
  float osc[4];
#pragma unroll
  for (int r = 0; r < 4; ++r) {
    float mn = fmaxf(mrow[r], tm[r]);
    osc[r] = __expf(mrow[r] - mn);
    mrow[r] = mn;
    lrow[r] *= osc[r];
  }
#pragma unroll
  for (int d = 0; d < 8; ++d)
#pragma unroll
    for (int r = 0; r < 4; ++r) oacc[d][r] *= osc[r];
  float rs[4] = {0.f, 0.f, 0.f, 0.f};
#pragma unroll
  for (int nf = 0; nf < 4; ++nf)
#pragma unroll
    for (int r = 0; r < 4; ++r) {
      float p = __expf(sv[nf][r] - mrow[r]);
      rs[r] += p;
      Psw[(lk * 4 + r) * 72 + nf * 16 + lq] = (bf16_t)p;
    }
#pragma unroll
  for (int r = 0; r < 4; ++r) {
    rs[r] += __shfl_xor(rs[r], 1);
    rs[r] += __shfl_xor(rs[r], 2);
    rs[r] += __shfl_xor(rs[r], 4);
    rs[r] += __shfl_xor(rs[r], 8);
    lrow[r] += rs[r];
  }
  // O += P V
#pragma unroll
  for (int s = 0; s < 2; ++s) {
    bf16x8 pa = *(const bf16x8*)&Psw[lq * 72 + s * 32 + lk * 8];
#pragma unroll
    for (int df = 0; df < 8; ++df) {
      int d = df * 16 + lq;
      int o = d * 128 + (((s * 32 + lk * 8) * 2) ^ ((d & 7) << 4));
      bf16x8 vb = *(const bf16x8*)((const char*)Vs + o);
      oacc[df] = __builtin_amdgcn_mfma_f32_16x16x32_bf16(pa, vb, oacc[df], 0, 0, 0);
    }
  }
}

__global__ __launch_bounds__(256) void attn_kernel(const bf16_t* __restrict__ qkv,
                                                   const bf16_t* __restrict__ vt,
                                                   unsigned short* __restrict__ y) {
  constexpr int KVBLK = 64;
  constexpr int NQT = T / KVBLK;  // 32
  __shared__ __align__(16) bf16_t Ks[KVBLK * DH];   // [kv][d], XOR-swizzled
  __shared__ __align__(16) bf16_t Vs[DH * KVBLK];   // [d][kv], XOR-swizzled
  __shared__ __align__(16) bf16_t Ps[4][16][72];    // per-wave P, padded rows
  const int tid = threadIdx.x;
  const int wid = tid >> 6, lane = tid & 63;
  const int lq = lane & 15, lk = lane >> 4;
  const int bh = blockIdx.x;              // same-bh blocks -> same XCD (id % 8 == bh % 8)
  const int j = blockIdx.y;               // pair index 0..15
  const int b = bh >> 4, h = bh & 15;
  const float scale = 0.08838834764831845f;  // 1/sqrt(128)

  const int qtL = j, qtH = NQT - 1 - j;
  const size_t rowbase = (size_t)(b * T) * N1;
  const int qloL = qtL * KVBLK + wid * 16;
  const int qloH = qtH * KVBLK + wid * 16;

  bf16x8 qfL[4], qfH[4];
  {
    const bf16_t* QgL = qkv + rowbase + (size_t)(qloL + lq) * N1 + h * DH;
    const bf16_t* QgH = qkv + rowbase + (size_t)(qloH + lq) * N1 + h * DH;
#pragma unroll
    for (int kk = 0; kk < 4; ++kk) {
      qfL[kk] = *(const bf16x8*)(QgL + kk * 32 + lk * 8);
      qfH[kk] = *(const bf16x8*)(QgH + kk * 32 + lk * 8);
    }
  }

  f32x4 oL[8] = {}, oH[8] = {};
  float mL[4] = {-1e30f, -1e30f, -1e30f, -1e30f}, lLr[4] = {0.f, 0.f, 0.f, 0.f};
  float mH[4] = {-1e30f, -1e30f, -1e30f, -1e30f}, lHr[4] = {0.f, 0.f, 0.f, 0.f};

  const bf16_t* Kg0 = qkv + rowbase + Cdim + h * DH;
  const bf16_t* Vg0 = vt + (size_t)bh * DH * T;
  bf16_t* Psw = &Ps[wid][0][0];

  const int ntiles = qtH + 1;
  for (int t = 0; t < ntiles; ++t) {
    const int kv0 = t * KVBLK;
    __syncthreads();
    // stage K tile [64][128], swizzled source -> linear LDS
#pragma unroll
    for (int i = 0; i < 4; ++i) {
      int p = wid * 4096 + i * 1024 + lane * 16;
      int r = p >> 8;
      int csw = (p & 255) ^ ((r & 7) << 4);
      gload_lds16(Kg0 + (size_t)(kv0 + r) * N1 + (csw >> 1), (char*)Ks + (wid * 4096 + i * 1024));
    }
    // stage Vt tile [128][64], swizzled source -> linear LDS
#pragma unroll
    for (int i = 0; i < 4; ++i) {
      int p = wid * 4096 + i * 1024 + lane * 16;
      int r = p >> 7;
      int csw = (p & 127) ^ ((r & 7) << 4);
      gload_lds16(Vg0 + (size_t)r * T + kv0 + (csw >> 1), (char*)Vs + (wid * 4096 + i * 1024));
    }
    __syncthreads();

    attn_process(Ks, Vs, Psw, qfH, oH, mH, lHr, qloH, kv0, lq, lk, scale);
    if (t <= qtL)
      attn_process(Ks, Vs, Psw, qfL, oL, mL, lLr, qloL, kv0, lq, lk, scale);
  }

#pragma unroll
  for (int r = 0; r < 4; ++r) {
    float invH = 1.0f / lHr[r];
    float invL = 1.0f / lLr[r];
    int qH = qloH + lk * 4 + r;
    int qL = qloL + lk * 4 + r;
    unsigned short* yH = y + (size_t)(b * T + qH) * Cdim + h * DH;
    unsigned short* yL = y + (size_t)(b * T + qL) * Cdim + h * DH;
#pragma unroll
    for (int df = 0; df < 8; ++df) {
      yH[df * 16 + lq] = f2bf(oH[df][r] * invH);
      yL[df * 16 + lq] = f2bf(oL[df][r] * invL);
    }
  }
}

extern "C" void kernel_launch(void* const* d_in, const int* in_sizes, int n_in,
                              void* d_out, int out_size, void* d_ws, size_t ws_size,
                              hipStream_t stream) {
  const float* x  = (const float*)d_in[0];
  const float* Wa = (const float*)d_in[1];
  const float* Wp = (const float*)d_in[2];
  float* out = (float*)d_out;
  char* ws = (char*)d_ws;

  // workspace layout (bytes): total ~117.4 MB
  size_t o0 = 0;                            // xb : M*K1 bf16 -- reused as Vt after gemm1
  size_t o1 = o0 + (size_t)M * K1 * 2;      // WaT: N1*K1 bf16
  size_t o2 = o1 + (size_t)N1 * K1 * 2;     // qkv: M*N1 bf16
  size_t o3 = o2 + (size_t)M * N1 * 2;      // yb : M*C bf16
  size_t o4 = o3 + (size_t)M * Cdim * 2;    // WpT: C*C bf16

  unsigned short* xb   = (unsigned short*)(ws + o0);
  unsigned short* WaT  = (unsigned short*)(ws + o1);
  unsigned short* qkvb = (unsigned short*)(ws + o2);
  unsigned short* yb   = (unsigned short*)(ws + o3);
  unsigned short* WpT  = (unsigned short*)(ws + o4);
  unsigned short* vtb  = xb;  // dead after gemm1; same size (M*K1 == B*NH*DH*T)

  cvt_kernel<<<dim3((M * K1 / 4 + 255) / 256), dim3(256), 0, stream>>>(x, xb, M * K1);
  transpose_cvt_kernel<<<dim3(N1 / 32, K1 / 32), dim3(32, 8), 0, stream>>>(Wa, WaT, K1, N1);
  transpose_cvt_kernel<<<dim3(Cdim / 32, Cdim / 32), dim3(32, 8), 0, stream>>>(Wp, WpT, Cdim, Cdim);

  gemm_bt<1><<<dim3(N1 / 128, M / 128), dim3(256), 0, stream>>>(
      (const bf16_t*)xb, (const bf16_t*)WaT, (void*)qkvb, M, N1, K1);

  vtrans_kernel<<<dim3(T / 32, DH / 32, Bsz * NH), dim3(32, 8), 0, stream>>>(qkvb, vtb);

  attn_kernel<<<dim3(Bsz * NH, T / 128), dim3(256), 0, stream>>>(
      (const bf16_t*)qkvb, (const bf16_t*)vtb, yb);

  gemm_bt<0><<<dim3(Cdim / 128, M / 128), dim3(256), 0, stream>>>(
      (const bf16_t*)yb, (const bf16_t*)WpT, (void*)out, M, Cdim, K1);
}

// Round 3
// 305.862 us; speedup vs baseline: 1.9346x; 1.1073x over previous
//
#include <hip/hip_runtime.h>
#include <hip/hip_bf16.h>
#include <stdint.h>

#define AS1 __attribute__((address_space(1)))
#define AS3 __attribute__((address_space(3)))

typedef __bf16 bf16_t;
typedef __bf16 bf16x8 __attribute__((ext_vector_type(8)));
typedef float f32x4 __attribute__((ext_vector_type(4)));

static constexpr int Bsz = 2, T = 2048, Cdim = 2048, NH = 16, DH = 128;
static constexpr int M  = Bsz * T;    // 4096
static constexpr int N1 = 3 * Cdim;   // 6144
static constexpr int K1 = Cdim;       // 2048

__device__ __forceinline__ unsigned short f2bf(float f) {
  unsigned u = __float_as_uint(f);
  u += 0x7fffu + ((u >> 16) & 1u);
  return (unsigned short)(u >> 16);
}

__device__ __forceinline__ void gload_lds16(const bf16_t* g, void* l) {
  __builtin_amdgcn_global_load_lds((AS1 const void*)g, (AS3 void*)l, 16, 0, 0);
}

// ---------------- fp32 -> bf16 elementwise convert (vec4) ----------------
__global__ void cvt_kernel(const float* __restrict__ in, unsigned short* __restrict__ out, int n) {
  int i = (blockIdx.x * blockDim.x + threadIdx.x) * 4;
  if (i >= n) return;
  float4 v = *(const float4*)(in + i);
  ushort4 o;
  o.x = f2bf(v.x); o.y = f2bf(v.y); o.z = f2bf(v.z); o.w = f2bf(v.w);
  *(ushort4*)(out + i) = o;
}

// ---------------- fp32 (KxN) -> bf16 transpose (NxK) ----------------
__global__ void transpose_cvt_kernel(const float* __restrict__ in, unsigned short* __restrict__ out,
                                     int K, int N) {
  __shared__ float tile[32][33];
  int n0 = blockIdx.x * 32, k0 = blockIdx.y * 32;
  int tx = threadIdx.x, ty = threadIdx.y;  // 32 x 8
#pragma unroll
  for (int i = 0; i < 32; i += 8)
    tile[ty + i][tx] = in[(size_t)(k0 + ty + i) * N + n0 + tx];
  __syncthreads();
#pragma unroll
  for (int i = 0; i < 32; i += 8)
    out[(size_t)(n0 + ty + i) * K + k0 + tx] = f2bf(tile[tx][ty + i]);
}

// ---------------- bf16 (T x DH slice of qkv V) -> bf16 Vt[bh][d][t] ----------------
__global__ void vtrans_kernel(const unsigned short* __restrict__ qkv, unsigned short* __restrict__ vt) {
  __shared__ unsigned short tile[32][33];
  int t0 = blockIdx.x * 32, d0 = blockIdx.y * 32, bh = blockIdx.z;
  int b = bh >> 4, h = bh & 15;
  int tx = threadIdx.x, ty = threadIdx.y;  // 32 x 8
  const unsigned short* src = qkv + (size_t)(b * T) * N1 + 2 * Cdim + h * DH;
#pragma unroll
  for (int i = 0; i < 32; i += 8)
    tile[ty + i][tx] = src[(size_t)(t0 + ty + i) * N1 + d0 + tx];
  __syncthreads();
  unsigned short* dst = vt + ((size_t)bh * DH + d0) * T + t0;
#pragma unroll
  for (int i = 0; i < 32; i += 8)
    dst[(size_t)(ty + i) * T + tx] = tile[tx][ty + i];
}

// ---------------- deep-pipelined bf16 GEMM: A (MxK) * BT (NxK) ----------------
// BM=128, BN=256, BK=32. 8 waves (2M x 4N), per-wave 64x64 output.
// Ring-4 LDS (96 KiB), prefetch 3 K-tiles ahead, counted vmcnt(6) at tile
// boundaries, raw s_barrier, setprio around MFMA cluster, XOR-swizzled LDS.
template <int OUT_BF16>
__global__ __launch_bounds__(512, 1) void gemm_p3(const bf16_t* __restrict__ A,
                                                  const bf16_t* __restrict__ BT,
                                                  void* __restrict__ Cp,
                                                  int Nn, int Kk) {
  constexpr int SLOT = 24576;  // A 8KB + B 16KB per ring slot
  __shared__ __align__(16) char ldsmem[4 * SLOT];
  char* ldsb = ldsmem;

  const int tid = threadIdx.x;
  const int wid = tid >> 6, lane = tid & 63;
  const int lq = lane & 15, lk = lane >> 4;
  const int wr = wid >> 2, wc = wid & 3;

  // XCD-aware bijective chunk swizzle (nwg % 8 == 0 for both GEMMs)
  const int nwg = gridDim.x;
  const int bid = blockIdx.x;
  const int q8 = nwg >> 3;
  const int sw = (bid & 7) * q8 + (bid >> 3);
  const int gx = Nn >> 8;          // N / 256
  const int tn = sw % gx;
  const int tm = sw / gx;

  f32x4 acc[4][4] = {};

  // ---- per-lane ds_read byte offsets within a slot (swizzled, tile-invariant)
  int aoff[4], boff[4];
#pragma unroll
  for (int m = 0; m < 4; ++m) {
    int row = wr * 64 + m * 16 + lq;
    aoff[m] = row * 64 + ((lk * 16) ^ (((row >> 1) & 3) << 4));
  }
#pragma unroll
  for (int n = 0; n < 4; ++n) {
    int brow = wc * 64 + n * 16 + lq;
    boff[n] = 8192 + brow * 64 + ((lk * 16) ^ (((brow >> 1) & 3) << 4));
  }

  // ---- per-lane staging source pointers (inverse-swizzled global, linear LDS)
  const int pA = wid * 1024 + lane * 16;         // byte in 8KB A tile
  const int arow = pA >> 6;
  const int acsw = (pA & 63) ^ (((arow >> 1) & 3) << 4);
  const bf16_t* Ags = A + (size_t)(tm * 128 + arow) * Kk + (acsw >> 1);

  const int pB0 = wid * 1024 + lane * 16;        // byte in first 8KB of B tile
  const int brow0 = pB0 >> 6;
  const int bcsw0 = (pB0 & 63) ^ (((brow0 >> 1) & 3) << 4);
  const bf16_t* Bgs0 = BT + (size_t)(tn * 256 + brow0) * Kk + (bcsw0 >> 1);

  const int pB1 = 8192 + wid * 1024 + lane * 16; // byte in second 8KB of B tile
  const int brow1 = pB1 >> 6;
  const int bcsw1 = (pB1 & 63) ^ (((brow1 >> 1) & 3) << 4);
  const bf16_t* Bgs1 = BT + (size_t)(tn * 256 + brow1) * Kk + (bcsw1 >> 1);

  const int ldsA = wid * 1024;
  const int ldsB0 = 8192 + wid * 1024;
  const int ldsB1 = 16384 + wid * 1024;

  auto stage = [&](int kt) {
    char* db = ldsb + ((kt & 3) * SLOT);
    gload_lds16(Ags + (size_t)kt * 32, db + ldsA);
    gload_lds16(Bgs0 + (size_t)kt * 32, db + ldsB0);
    gload_lds16(Bgs1 + (size_t)kt * 32, db + ldsB1);
  };

  const int nk = Kk >> 5;  // 64

  // prologue: stage tiles 0,1,2; guarantee tile 0 landed (allow 6 outstanding)
  stage(0); stage(1); stage(2);
  asm volatile("s_waitcnt vmcnt(6)" ::: "memory");
  __builtin_amdgcn_s_barrier();

#define TILE_BODY(KT, STAGE_EN, VM)                                              \
  {                                                                              \
    __builtin_amdgcn_sched_barrier(0);                                           \
    const int kt_ = (KT);                                                        \
    const char* sb = ldsb + ((kt_ & 3) * SLOT);                                  \
    bf16x8 af[4], bfv[4];                                                        \
    _Pragma("unroll") for (int m = 0; m < 4; ++m)                                \
      af[m] = *(const bf16x8*)(sb + aoff[m]);                                    \
    _Pragma("unroll") for (int n = 0; n < 4; ++n)                                \
      bfv[n] = *(const bf16x8*)(sb + boff[n]);                                   \
    if (STAGE_EN) stage(kt_ + 3);                                                \
    __builtin_amdgcn_sched_barrier(0);                                           \
    __builtin_amdgcn_s_barrier();                                                \
    asm volatile("s_waitcnt lgkmcnt(0)" ::: "memory");                           \
    __builtin_amdgcn_sched_barrier(0);                                           \
    __builtin_amdgcn_s_setprio(1);                                               \
    _Pragma("unroll") for (int m = 0; m < 4; ++m)                                \
      _Pragma("unroll") for (int n = 0; n < 4; ++n)                              \
        acc[m][n] =                                                              \
            __builtin_amdgcn_mfma_f32_16x16x32_bf16(af[m], bfv[n], acc[m][n], 0, 0, 0); \
    __builtin_amdgcn_s_setprio(0);                                               \
    __builtin_amdgcn_sched_barrier(0);                                           \
    asm volatile("s_waitcnt vmcnt(" #VM ")" ::: "memory");                       \
    __builtin_amdgcn_s_barrier();                                                \
  }

  for (int kt = 0; kt < nk - 3; ++kt) TILE_BODY(kt, 1, 6);
  TILE_BODY(nk - 3, 0, 3);
  TILE_BODY(nk - 2, 0, 0);
  TILE_BODY(nk - 1, 0, 0);
#undef TILE_BODY

  // epilogue
#pragma unroll
  for (int m = 0; m < 4; ++m)
#pragma unroll
    for (int n = 0; n < 4; ++n)
#pragma unroll
      for (int r = 0; r < 4; ++r) {
        int row = tm * 128 + wr * 64 + m * 16 + lk * 4 + r;
        int col = tn * 256 + wc * 64 + n * 16 + lq;
        if (OUT_BF16)
          ((unsigned short*)Cp)[(size_t)row * Nn + col] = f2bf(acc[m][n][r]);
        else
          ((float*)Cp)[(size_t)row * Nn + col] = acc[m][n][r];
      }
}

// ---------------- causal flash attention, balanced-pair blocks ----------------
__device__ __forceinline__ void attn_process(
    const bf16_t* __restrict__ Ks, const bf16_t* __restrict__ Vs, bf16_t* __restrict__ Psw,
    const bf16x8* qf, f32x4* oacc, float* mrow, float* lrow,
    int qlo, int kv0, int lq, int lk, float scale) {
  // S = Q K^T
  f32x4 sacc[4] = {};
#pragma unroll
  for (int nf = 0; nf < 4; ++nf) {
    int r = nf * 16 + lq;
    int sw = (r & 7) << 4;
#pragma unroll
    for (int kk = 0; kk < 4; ++kk) {
      bf16x8 kf = *(const bf16x8*)((const char*)Ks + r * 256 + ((64 * kk + 16 * lk) ^ sw));
      sacc[nf] = __builtin_amdgcn_mfma_f32_16x16x32_bf16(qf[kk], kf, sacc[nf], 0, 0, 0);
    }
  }
  // online softmax
  float sv[4][4];
  float tm[4] = {-1e30f, -1e30f, -1e30f, -1e30f};
#pragma unroll
  for (int nf = 0; nf < 4; ++nf) {
    int kv = kv0 + nf * 16 + lq;
#pragma unroll
    for (int r = 0; r < 4; ++r) {
      int q = qlo + lk * 4 + r;
      float s = sacc[nf][r] * scale;
      if (kv > q) s = -1e30f;
      sv[nf][r] = s;
      tm[r] = fmaxf(tm[r], s);
    }
  }
#pragma unroll
  for (int r = 0; r < 4; ++r) {
    tm[r] = fmaxf(tm[r], __shfl_xor(tm[r], 1));
    tm[r] = fmaxf(tm[r], __shfl_xor(tm[r], 2));
    tm[r] = fmaxf(tm[r], __shfl_xor(tm[r], 4));
    tm[r] = fmaxf(tm[r], __shfl_xor(tm[r], 8));
  }
  float osc[4];
#pragma unroll
  for (int r = 0; r < 4; ++r) {
    float mn = fmaxf(mrow[r], tm[r]);
    osc[r] = __expf(mrow[r] - mn);
    mrow[r] = mn;
    lrow[r] *= osc[r];
  }
#pragma unroll
  for (int d = 0; d < 8; ++d)
#pragma unroll
    for (int r = 0; r < 4; ++r) oacc[d][r] *= osc[r];
  float rs[4] = {0.f, 0.f, 0.f, 0.f};
#pragma unroll
  for (int nf = 0; nf < 4; ++nf)
#pragma unroll
    for (int r = 0; r < 4; ++r) {
      float p = __expf(sv[nf][r] - mrow[r]);
      rs[r] += p;
      Psw[(lk * 4 + r) * 72 + nf * 16 + lq] = (bf16_t)p;
    }
#pragma unroll
  for (int r = 0; r < 4; ++r) {
    rs[r] += __shfl_xor(rs[r], 1);
    rs[r] += __shfl_xor(rs[r], 2);
    rs[r] += __shfl_xor(rs[r], 4);
    rs[r] += __shfl_xor(rs[r], 8);
    lrow[r] += rs[r];
  }
  // O += P V
#pragma unroll
  for (int s = 0; s < 2; ++s) {
    bf16x8 pa = *(const bf16x8*)&Psw[lq * 72 + s * 32 + lk * 8];
#pragma unroll
    for (int df = 0; df < 8; ++df) {
      int d = df * 16 + lq;
      int o = d * 128 + (((s * 32 + lk * 8) * 2) ^ ((d & 7) << 4));
      bf16x8 vb = *(const bf16x8*)((const char*)Vs + o);
      oacc[df] = __builtin_amdgcn_mfma_f32_16x16x32_bf16(pa, vb, oacc[df], 0, 0, 0);
    }
  }
}

__global__ __launch_bounds__(256) void attn_kernel(const bf16_t* __restrict__ qkv,
                                                   const bf16_t* __restrict__ vt,
                                                   unsigned short* __restrict__ y) {
  constexpr int KVBLK = 64;
  constexpr int NQT = T / KVBLK;  // 32
  __shared__ __align__(16) bf16_t Ks[KVBLK * DH];
  __shared__ __align__(16) bf16_t Vs[DH * KVBLK];
  __shared__ __align__(16) bf16_t Ps[4][16][72];
  const int tid = threadIdx.x;
  const int wid = tid >> 6, lane = tid & 63;
  const int lq = lane & 15, lk = lane >> 4;
  const int bh = blockIdx.x;
  const int j = blockIdx.y;
  const int b = bh >> 4, h = bh & 15;
  const float scale = 0.08838834764831845f;

  const int qtL = j, qtH = NQT - 1 - j;
  const size_t rowbase = (size_t)(b * T) * N1;
  const int qloL = qtL * KVBLK + wid * 16;
  const int qloH = qtH * KVBLK + wid * 16;

  bf16x8 qfL[4], qfH[4];
  {
    const bf16_t* QgL = qkv + rowbase + (size_t)(qloL + lq) * N1 + h * DH;
    const bf16_t* QgH = qkv + rowbase + (size_t)(qloH + lq) * N1 + h * DH;
#pragma unroll
    for (int kk = 0; kk < 4; ++kk) {
      qfL[kk] = *(const bf16x8*)(QgL + kk * 32 + lk * 8);
      qfH[kk] = *(const bf16x8*)(QgH + kk * 32 + lk * 8);
    }
  }

  f32x4 oL[8] = {}, oH[8] = {};
  float mL[4] = {-1e30f, -1e30f, -1e30f, -1e30f}, lLr[4] = {0.f, 0.f, 0.f, 0.f};
  float mH[4] = {-1e30f, -1e30f, -1e30f, -1e30f}, lHr[4] = {0.f, 0.f, 0.f, 0.f};

  const bf16_t* Kg0 = qkv + rowbase + Cdim + h * DH;
  const bf16_t* Vg0 = vt + (size_t)bh * DH * T;
  bf16_t* Psw = &Ps[wid][0][0];

  const int ntiles = qtH + 1;
  for (int t = 0; t < ntiles; ++t) {
    const int kv0 = t * KVBLK;
    __syncthreads();
#pragma unroll
    for (int i = 0; i < 4; ++i) {
      int p = wid * 4096 + i * 1024 + lane * 16;
      int r = p >> 8;
      int csw = (p & 255) ^ ((r & 7) << 4);
      gload_lds16(Kg0 + (size_t)(kv0 + r) * N1 + (csw >> 1), (char*)Ks + (wid * 4096 + i * 1024));
    }
#pragma unroll
    for (int i = 0; i < 4; ++i) {
      int p = wid * 4096 + i * 1024 + lane * 16;
      int r = p >> 7;
      int csw = (p & 127) ^ ((r & 7) << 4);
      gload_lds16(Vg0 + (size_t)r * T + kv0 + (csw >> 1), (char*)Vs + (wid * 4096 + i * 1024));
    }
    __syncthreads();

    attn_process(Ks, Vs, Psw, qfH, oH, mH, lHr, qloH, kv0, lq, lk, scale);
    if (t <= qtL)
      attn_process(Ks, Vs, Psw, qfL, oL, mL, lLr, qloL, kv0, lq, lk, scale);
  }

#pragma unroll
  for (int r = 0; r < 4; ++r) {
    float invH = 1.0f / lHr[r];
    float invL = 1.0f / lLr[r];
    int qH = qloH + lk * 4 + r;
    int qL = qloL + lk * 4 + r;
    unsigned short* yH = y + (size_t)(b * T + qH) * Cdim + h * DH;
    unsigned short* yL = y + (size_t)(b * T + qL) * Cdim + h * DH;
#pragma unroll
    for (int df = 0; df < 8; ++df) {
      yH[df * 16 + lq] = f2bf(oH[df][r] * invH);
      yL[df * 16 + lq] = f2bf(oL[df][r] * invL);
    }
  }
}

extern "C" void kernel_launch(void* const* d_in, const int* in_sizes, int n_in,
                              void* d_out, int out_size, void* d_ws, size_t ws_size,
                              hipStream_t stream) {
  const float* x  = (const float*)d_in[0];
  const float* Wa = (const float*)d_in[1];
  const float* Wp = (const float*)d_in[2];
  float* out = (float*)d_out;
  char* ws = (char*)d_ws;

  size_t o0 = 0;                            // xb : M*K1 bf16 -- reused as Vt after gemm1
  size_t o1 = o0 + (size_t)M * K1 * 2;      // WaT: N1*K1 bf16
  size_t o2 = o1 + (size_t)N1 * K1 * 2;     // qkv: M*N1 bf16
  size_t o3 = o2 + (size_t)M * N1 * 2;      // yb : M*C bf16
  size_t o4 = o3 + (size_t)M * Cdim * 2;    // WpT: C*C bf16

  unsigned short* xb   = (unsigned short*)(ws + o0);
  unsigned short* WaT  = (unsigned short*)(ws + o1);
  unsigned short* qkvb = (unsigned short*)(ws + o2);
  unsigned short* yb   = (unsigned short*)(ws + o3);
  unsigned short* WpT  = (unsigned short*)(ws + o4);
  unsigned short* vtb  = xb;

  cvt_kernel<<<dim3((M * K1 / 4 + 255) / 256), dim3(256), 0, stream>>>(x, xb, M * K1);
  transpose_cvt_kernel<<<dim3(N1 / 32, K1 / 32), dim3(32, 8), 0, stream>>>(Wa, WaT, K1, N1);
  transpose_cvt_kernel<<<dim3(Cdim / 32, Cdim / 32), dim3(32, 8), 0, stream>>>(Wp, WpT, Cdim, Cdim);

  // qkv GEMM: grid = (4096/128)*(6144/256) = 32*24 = 768 blocks (3 full CU rounds)
  gemm_p3<1><<<dim3((M / 128) * (N1 / 256)), dim3(512), 0, stream>>>(
      (const bf16_t*)xb, (const bf16_t*)WaT, (void*)qkvb, N1, K1);

  vtrans_kernel<<<dim3(T / 32, DH / 32, Bsz * NH), dim3(32, 8), 0, stream>>>(qkvb, vtb);

  attn_kernel<<<dim3(Bsz * NH, T / 128), dim3(256), 0, stream>>>(
      (const bf16_t*)qkvb, (const bf16_t*)vtb, yb);

  // proj GEMM: grid = (4096/128)*(2048/256) = 32*8 = 256 blocks (1 full round)
  gemm_p3<0><<<dim3((M / 128) * (Cdim / 256)), dim3(512), 0, stream>>>(
      (const bf16_t*)yb, (const bf16_t*)WpT, (void*)out, Cdim, K1);
}

// Round 5
// 253.421 us; speedup vs baseline: 2.3349x; 1.2069x over previous
//
#include <hip/hip_runtime.h>
#include <hip/hip_bf16.h>
#include <stdint.h>

#define AS1 __attribute__((address_space(1)))
#define AS3 __attribute__((address_space(3)))

typedef __bf16 bf16_t;
typedef __bf16 bf16x8 __attribute__((ext_vector_type(8)));
typedef float f32x4 __attribute__((ext_vector_type(4)));
typedef float f32x16 __attribute__((ext_vector_type(16)));

static constexpr int Bsz = 2, T = 2048, Cdim = 2048, NH = 16, DH = 128;
static constexpr int M  = Bsz * T;    // 4096
static constexpr int N1 = 3 * Cdim;   // 6144
static constexpr int K1 = Cdim;       // 2048

__device__ __forceinline__ unsigned short f2bf(float f) {
  unsigned u = __float_as_uint(f);
  u += 0x7fffu + ((u >> 16) & 1u);
  return (unsigned short)(u >> 16);
}

__device__ __forceinline__ void gload_lds16(const bf16_t* g, void* l) {
  __builtin_amdgcn_global_load_lds((AS1 const void*)g, (AS3 void*)l, 16, 0, 0);
}

__device__ __forceinline__ float ex2(float x) {
  float r; asm("v_exp_f32 %0, %1" : "=v"(r) : "v"(x)); return r;
}
__device__ __forceinline__ unsigned pk2(float a, float b) {
  unsigned r; asm("v_cvt_pk_bf16_f32 %0, %1, %2" : "=v"(r) : "v"(a), "v"(b)); return r;
}

// ---------------- fp32 -> bf16 elementwise convert (vec4) ----------------
__global__ void cvt_kernel(const float* __restrict__ in, unsigned short* __restrict__ out, int n) {
  int i = (blockIdx.x * blockDim.x + threadIdx.x) * 4;
  if (i >= n) return;
  float4 v = *(const float4*)(in + i);
  ushort4 o;
  o.x = f2bf(v.x); o.y = f2bf(v.y); o.z = f2bf(v.z); o.w = f2bf(v.w);
  *(ushort4*)(out + i) = o;
}

// ---------------- fp32 (KxN) -> bf16 transpose (NxK) ----------------
__global__ void transpose_cvt_kernel(const float* __restrict__ in, unsigned short* __restrict__ out,
                                     int K, int N) {
  __shared__ float tile[32][33];
  int n0 = blockIdx.x * 32, k0 = blockIdx.y * 32;
  int tx = threadIdx.x, ty = threadIdx.y;  // 32 x 8
#pragma unroll
  for (int i = 0; i < 32; i += 8)
    tile[ty + i][tx] = in[(size_t)(k0 + ty + i) * N + n0 + tx];
  __syncthreads();
#pragma unroll
  for (int i = 0; i < 32; i += 8)
    out[(size_t)(n0 + ty + i) * K + k0 + tx] = f2bf(tile[tx][ty + i]);
}

// ---------------- bf16 (T x DH slice of qkv V) -> bf16 Vt[bh][d][t] ----------------
__global__ void vtrans_kernel(const unsigned short* __restrict__ qkv, unsigned short* __restrict__ vt) {
  __shared__ unsigned short tile[32][33];
  int t0 = blockIdx.x * 32, d0 = blockIdx.y * 32, bh = blockIdx.z;
  int b = bh >> 4, h = bh & 15;
  int tx = threadIdx.x, ty = threadIdx.y;  // 32 x 8
  const unsigned short* src = qkv + (size_t)(b * T) * N1 + 2 * Cdim + h * DH;
#pragma unroll
  for (int i = 0; i < 32; i += 8)
    tile[ty + i][tx] = src[(size_t)(t0 + ty + i) * N1 + d0 + tx];
  __syncthreads();
  unsigned short* dst = vt + ((size_t)bh * DH + d0) * T + t0;
#pragma unroll
  for (int i = 0; i < 32; i += 8)
    dst[(size_t)(ty + i) * T + tx] = tile[tx][ty + i];
}

// ---------------- deep-pipelined bf16 GEMM: A (MxK) * BT (NxK) ----------------
template <int OUT_BF16>
__global__ __launch_bounds__(512, 1) void gemm_p3(const bf16_t* __restrict__ A,
                                                  const bf16_t* __restrict__ BT,
                                                  void* __restrict__ Cp,
                                                  int Nn, int Kk) {
  constexpr int SLOT = 24576;
  __shared__ __align__(16) char ldsmem[4 * SLOT];
  char* ldsb = ldsmem;

  const int tid = threadIdx.x;
  const int wid = tid >> 6, lane = tid & 63;
  const int lq = lane & 15, lk = lane >> 4;
  const int wr = wid >> 2, wc = wid & 3;

  const int nwg = gridDim.x;
  const int bid = blockIdx.x;
  const int q8 = nwg >> 3;
  const int sw = (bid & 7) * q8 + (bid >> 3);
  const int gx = Nn >> 8;
  const int tn = sw % gx;
  const int tm = sw / gx;

  f32x4 acc[4][4] = {};

  int aoff[4], boff[4];
#pragma unroll
  for (int m = 0; m < 4; ++m) {
    int row = wr * 64 + m * 16 + lq;
    aoff[m] = row * 64 + ((lk * 16) ^ (((row >> 1) & 3) << 4));
  }
#pragma unroll
  for (int n = 0; n < 4; ++n) {
    int brow = wc * 64 + n * 16 + lq;
    boff[n] = 8192 + brow * 64 + ((lk * 16) ^ (((brow >> 1) & 3) << 4));
  }

  const int pA = wid * 1024 + lane * 16;
  const int arow = pA >> 6;
  const int acsw = (pA & 63) ^ (((arow >> 1) & 3) << 4);
  const bf16_t* Ags = A + (size_t)(tm * 128 + arow) * Kk + (acsw >> 1);

  const int pB0 = wid * 1024 + lane * 16;
  const int brow0 = pB0 >> 6;
  const int bcsw0 = (pB0 & 63) ^ (((brow0 >> 1) & 3) << 4);
  const bf16_t* Bgs0 = BT + (size_t)(tn * 256 + brow0) * Kk + (bcsw0 >> 1);

  const int pB1 = 8192 + wid * 1024 + lane * 16;
  const int brow1 = pB1 >> 6;  // 128..255
  const int bcsw1 = (pB1 & 63) ^ (((brow1 >> 1) & 3) << 4);
  const bf16_t* Bgs1 = BT + (size_t)(tn * 256 + brow1) * Kk + (bcsw1 >> 1);

  const int ldsA = wid * 1024;
  const int ldsB0 = 8192 + wid * 1024;
  const int ldsB1 = 16384 + wid * 1024;

  auto stage = [&](int kt) {
    char* db = ldsb + ((kt & 3) * SLOT);
    gload_lds16(Ags + (size_t)kt * 32, db + ldsA);
    gload_lds16(Bgs0 + (size_t)kt * 32, db + ldsB0);
    gload_lds16(Bgs1 + (size_t)kt * 32, db + ldsB1);
  };

  const int nk = Kk >> 5;

  stage(0); stage(1); stage(2);
  asm volatile("s_waitcnt vmcnt(6)" ::: "memory");
  __builtin_amdgcn_s_barrier();

#define TILE_BODY(KT, STAGE_EN, VM)                                              \
  {                                                                              \
    __builtin_amdgcn_sched_barrier(0);                                           \
    const int kt_ = (KT);                                                        \
    const char* sb = ldsb + ((kt_ & 3) * SLOT);                                  \
    bf16x8 af[4], bfv[4];                                                        \
    _Pragma("unroll") for (int m = 0; m < 4; ++m)                                \
      af[m] = *(const bf16x8*)(sb + aoff[m]);                                    \
    _Pragma("unroll") for (int n = 0; n < 4; ++n)                                \
      bfv[n] = *(const bf16x8*)(sb + boff[n]);                                   \
    if (STAGE_EN) stage(kt_ + 3);                                                \
    __builtin_amdgcn_sched_barrier(0);                                           \
    __builtin_amdgcn_s_barrier();                                                \
    asm volatile("s_waitcnt lgkmcnt(0)" ::: "memory");                           \
    __builtin_amdgcn_sched_barrier(0);                                           \
    __builtin_amdgcn_s_setprio(1);                                               \
    _Pragma("unroll") for (int m = 0; m < 4; ++m)                                \
      _Pragma("unroll") for (int n = 0; n < 4; ++n)                              \
        acc[m][n] =                                                              \
            __builtin_amdgcn_mfma_f32_16x16x32_bf16(af[m], bfv[n], acc[m][n], 0, 0, 0); \
    __builtin_amdgcn_s_setprio(0);                                               \
    __builtin_amdgcn_sched_barrier(0);                                           \
    asm volatile("s_waitcnt vmcnt(" #VM ")" ::: "memory");                       \
    __builtin_amdgcn_s_barrier();                                                \
  }

  for (int kt = 0; kt < nk - 3; ++kt) TILE_BODY(kt, 1, 6);
  TILE_BODY(nk - 3, 0, 3);
  TILE_BODY(nk - 2, 0, 0);
  TILE_BODY(nk - 1, 0, 0);
#undef TILE_BODY

#pragma unroll
  for (int m = 0; m < 4; ++m)
#pragma unroll
    for (int n = 0; n < 4; ++n)
#pragma unroll
      for (int r = 0; r < 4; ++r) {
        int row = tm * 128 + wr * 64 + m * 16 + lk * 4 + r;
        int col = tn * 256 + wc * 64 + n * 16 + lq;
        if (OUT_BF16)
          ((unsigned short*)Cp)[(size_t)row * Nn + col] = f2bf(acc[m][n][r]);
        else
          ((float*)Cp)[(size_t)row * Nn + col] = acc[m][n][r];
      }
}

// ---------------- causal flash attention: swapped-QK^T 32x32, 8 waves ----------------
// Waves 0-3: q-group g; waves 4-7: q-group 15-g (balanced pairing).
// S^T = mfma(K, Q): q = lane&31 lane-local. O^T = mfma(V^T, P^T). P in registers.
__global__ __launch_bounds__(512, 1) void attn_kernel(const bf16_t* __restrict__ qkv,
                                                      const bf16_t* __restrict__ vt,
                                                      unsigned short* __restrict__ y) {
  __shared__ __align__(16) char lds[65536];  // K dbuf 2x16KB @0, V dbuf 2x16KB @32768
  const int tid = threadIdx.x;
  const int wid = tid >> 6, lane = tid & 63;
  const int l31 = lane & 31, hi = lane >> 5;
  const int hi16 = hi << 4;
  const int bh = blockIdx.x;
  const int g = blockIdx.y;              // pair index 0..7
  const int b = bh >> 4, h = bh & 15;
  const float SC2 = 0.12751879868954096f;  // (1/sqrt(128)) * log2(e)

  const int grp = (wid < 4) ? g : (15 - g);
  const int qlo = grp * 128 + (wid & 3) * 32;
  const int qidx = qlo + l31;
  const int nt = 2 * (15 - g) + 2;        // tiles staged (covers H region)
  const size_t rowbase = (size_t)(b * T) * N1;

  // Q fragments: qf[kk] elem j = Q[qlo+l31][16kk + 8hi + j]
  bf16x8 qf[8];
  {
    const bf16_t* Qg = qkv + rowbase + (size_t)qidx * N1 + h * DH + hi * 8;
#pragma unroll
    for (int kk = 0; kk < 8; ++kk) qf[kk] = *(const bf16x8*)(Qg + kk * 16);
  }

  // staging source pointers (inverse-swizzled global, linear LDS dest)
  const bf16_t* Kg0 = qkv + rowbase + Cdim + h * DH;
  const bf16_t* Vg0 = vt + (size_t)bh * DH * T;
  const int p0 = wid * 1024 + lane * 16;
  const int p1 = 8192 + wid * 1024 + lane * 16;
  const int kr0 = p0 >> 8, kr1 = p1 >> 8;
  const bf16_t* KsA = Kg0 + (size_t)kr0 * N1 + ((((p0 & 255) ^ ((kr0 & 15) << 4))) >> 1);
  const bf16_t* KsB = Kg0 + (size_t)kr1 * N1 + ((((p1 & 255) ^ ((kr1 & 15) << 4))) >> 1);
  const int vr0 = p0 >> 7, vr1 = p1 >> 7;
  const bf16_t* VsA = Vg0 + (size_t)vr0 * T + ((((p0 & 127) ^ ((vr0 & 7) << 4))) >> 1);
  const bf16_t* VsB = Vg0 + (size_t)vr1 * T + ((((p1 & 127) ^ ((vr1 & 7) << 4))) >> 1);
  const int dstoff = wid * 1024;

  auto stage = [&](int tt) {
    char* Kd = lds + (tt & 1) * 16384;
    char* Vd = lds + 32768 + (tt & 1) * 16384;
    const size_t ko = (size_t)(tt * 64) * N1;
    const int vo = tt * 64;
    gload_lds16(KsA + ko, Kd + dstoff);
    gload_lds16(KsB + ko, Kd + 8192 + dstoff);
    gload_lds16(VsA + vo, Vd + dstoff);
    gload_lds16(VsB + vo, Vd + 8192 + dstoff);
  };

  f32x16 oacc[4] = {};
  float mrow = -1e30f, lrow = 0.f;

  stage(0);
  asm volatile("s_waitcnt vmcnt(0)" ::: "memory");
  __builtin_amdgcn_s_barrier();

  for (int t = 0; t < nt; ++t) {
    const int kv0 = t * 64;
    if (t + 1 < nt) stage(t + 1);

    if (kv0 <= qlo + 31) {
      // ---- S^T = K Q^T ----
      f32x16 s0 = {}, s1 = {};
      {
        const char* Kb = lds + (t & 1) * 16384;
        const char* krow0 = Kb + l31 * 256;
        const char* krow1 = Kb + (32 + l31) * 256;
        const int sw0 = (l31 & 15) << 4;
        const int sw1 = ((32 + l31) & 15) << 4;  // == sw0
#pragma unroll
        for (int kk = 0; kk < 8; ++kk) {
          bf16x8 kf0 = *(const bf16x8*)(krow0 + ((kk * 32 + hi16) ^ sw0));
          bf16x8 kf1 = *(const bf16x8*)(krow1 + ((kk * 32 + hi16) ^ sw1));
          s0 = __builtin_amdgcn_mfma_f32_32x32x16_bf16(kf0, qf[kk], s0, 0, 0, 0);
          s1 = __builtin_amdgcn_mfma_f32_32x32x16_bf16(kf1, qf[kk], s1, 0, 0, 0);
        }
      }
      float sv[32];
#pragma unroll
      for (int r = 0; r < 16; ++r) { sv[r] = s0[r]; sv[16 + r] = s1[r]; }
      if (kv0 + 63 > qlo) {  // (partially) diagonal tile: causal mask
#pragma unroll
        for (int r = 0; r < 16; ++r) {
          const int roff = (r & 3) + 8 * (r >> 2);
          if (kv0 + roff + 4 * hi > qidx) sv[r] = -1e30f;
          if (kv0 + 32 + roff + 4 * hi > qidx) sv[16 + r] = -1e30f;
        }
      }
      // ---- online softmax (q lane-local) ----
      float mx = sv[0];
#pragma unroll
      for (int i = 1; i < 32; ++i) mx = fmaxf(mx, sv[i]);
      mx = fmaxf(mx, __shfl_xor(mx, 32));
      const float mn = fmaxf(mrow, mx);
      const float osc = ex2((mrow - mn) * SC2);
      mrow = mn;
      const float mn2 = mn * SC2;
#pragma unroll
      for (int db = 0; db < 4; ++db) oacc[db] *= osc;
      float srow = 0.f;
#pragma unroll
      for (int i = 0; i < 32; ++i) {
        float p = ex2(fmaf(sv[i], SC2, -mn2));
        sv[i] = p;
        srow += p;
      }
      srow += __shfl_xor(srow, 32);
      lrow = lrow * osc + srow;
      // ---- build P^T B-fragments in-register (cvt_pk + lane^32 exchange) ----
      bf16x8 pb[4];
#pragma unroll
      for (int s4 = 0; s4 < 4; ++s4) {
        const int base = (s4 >> 1) * 16 + (s4 & 1) * 8;
        unsigned x0 = pk2(sv[base + 0], sv[base + 1]);
        unsigned x1 = pk2(sv[base + 2], sv[base + 3]);
        unsigned y0 = pk2(sv[base + 4], sv[base + 5]);
        unsigned y1 = pk2(sv[base + 6], sv[base + 7]);
        unsigned e0 = (unsigned)__shfl_xor((int)(hi ? x0 : y0), 32);
        unsigned e1 = (unsigned)__shfl_xor((int)(hi ? x1 : y1), 32);
        union { unsigned u[4]; bf16x8 v; } pbu;
        pbu.u[0] = hi ? e0 : x0;
        pbu.u[1] = hi ? e1 : x1;
        pbu.u[2] = hi ? y0 : e0;
        pbu.u[3] = hi ? y1 : e1;
        pb[s4] = pbu.v;
      }
      // ---- O^T += V^T P^T ----
      {
        const char* Vb = lds + 32768 + (t & 1) * 16384;
#pragma unroll
        for (int db = 0; db < 4; ++db) {
          const int vrow = db * 32 + l31;
          const char* vr = Vb + vrow * 128;
          const int swv = (vrow & 7) << 4;
#pragma unroll
          for (int s4 = 0; s4 < 4; ++s4) {
            bf16x8 vf = *(const bf16x8*)(vr + ((s4 * 32 + hi16) ^ swv));
            oacc[db] = __builtin_amdgcn_mfma_f32_32x32x16_bf16(vf, pb[s4], oacc[db], 0, 0, 0);
          }
        }
      }
    }

    asm volatile("s_waitcnt vmcnt(0)" ::: "memory");
    __builtin_amdgcn_s_barrier();
  }

  // ---- epilogue: O^T[d][q] -> y[q][d] via per-wave LDS transpose ----
  const float inv = 1.0f / lrow;
  char* eb = lds + wid * 8192;  // 32 rows x 256 B, swizzled
#pragma unroll
  for (int db = 0; db < 4; ++db)
#pragma unroll
    for (int r = 0; r < 16; ++r) {
      const int d = db * 32 + (r & 3) + 8 * (r >> 2) + 4 * hi;
      const int off = l31 * 256 + ((d * 2) ^ ((l31 & 15) << 4));
      *(unsigned short*)(eb + off) = f2bf(oacc[db][r] * inv);
    }
  asm volatile("s_waitcnt lgkmcnt(0)" ::: "memory");
  __builtin_amdgcn_sched_barrier(0);
  {
    unsigned short* yr = y + (size_t)(b * T + qlo + l31) * Cdim + h * DH;
#pragma unroll
    for (int rr = 0; rr < 8; ++rr) {
      const int c = hi * 8 + rr;  // 0..15 -> d = c*8 .. c*8+7 (full 128)
      bf16x8 v = *(const bf16x8*)(eb + l31 * 256 + ((c * 16) ^ ((l31 & 15) << 4)));
      *(bf16x8*)(yr + c * 8) = v;
    }
  }
}

extern "C" void kernel_launch(void* const* d_in, const int* in_sizes, int n_in,
                              void* d_out, int out_size, void* d_ws, size_t ws_size,
                              hipStream_t stream) {
  const float* x  = (const float*)d_in[0];
  const float* Wa = (const float*)d_in[1];
  const float* Wp = (const float*)d_in[2];
  float* out = (float*)d_out;
  char* ws = (char*)d_ws;

  size_t o0 = 0;                            // xb : M*K1 bf16 -- reused as Vt after gemm1
  size_t o1 = o0 + (size_t)M * K1 * 2;      // WaT: N1*K1 bf16
  size_t o2 = o1 + (size_t)N1 * K1 * 2;     // qkv: M*N1 bf16
  size_t o3 = o2 + (size_t)M * N1 * 2;      // yb : M*C bf16
  size_t o4 = o3 + (size_t)M * Cdim * 2;    // WpT: C*C bf16

  unsigned short* xb   = (unsigned short*)(ws + o0);
  unsigned short* WaT  = (unsigned short*)(ws + o1);
  unsigned short* qkvb = (unsigned short*)(ws + o2);
  unsigned short* yb   = (unsigned short*)(ws + o3);
  unsigned short* WpT  = (unsigned short*)(ws + o4);
  unsigned short* vtb  = xb;

  cvt_kernel<<<dim3((M * K1 / 4 + 255) / 256), dim3(256), 0, stream>>>(x, xb, M * K1);
  transpose_cvt_kernel<<<dim3(N1 / 32, K1 / 32), dim3(32, 8), 0, stream>>>(Wa, WaT, K1, N1);
  transpose_cvt_kernel<<<dim3(Cdim / 32, Cdim / 32), dim3(32, 8), 0, stream>>>(Wp, WpT, Cdim, Cdim);

  gemm_p3<1><<<dim3((M / 128) * (N1 / 256)), dim3(512), 0, stream>>>(
      (const bf16_t*)xb, (const bf16_t*)WaT, (void*)qkvb, N1, K1);

  vtrans_kernel<<<dim3(T / 32, DH / 32, Bsz * NH), dim3(32, 8), 0, stream>>>(qkvb, vtb);

  attn_kernel<<<dim3(Bsz * NH, 8), dim3(512), 0, stream>>>(
      (const bf16_t*)qkvb, (const bf16_t*)vtb, yb);

  gemm_p3<0><<<dim3((M / 128) * (Cdim / 256)), dim3(512), 0, stream>>>(
      (const bf16_t*)yb, (const bf16_t*)WpT, (void*)out, Cdim, K1);
}

// Round 6
// 249.586 us; speedup vs baseline: 2.3708x; 1.0154x over previous
//
#include <hip/hip_runtime.h>
#include <hip/hip_bf16.h>
#include <stdint.h>

#define AS1 __attribute__((address_space(1)))
#define AS3 __attribute__((address_space(3)))

typedef __bf16 bf16_t;
typedef __bf16 bf16x8 __attribute__((ext_vector_type(8)));
typedef float f32x4 __attribute__((ext_vector_type(4)));
typedef float f32x16 __attribute__((ext_vector_type(16)));

static constexpr int Bsz = 2, T = 2048, Cdim = 2048, NH = 16, DH = 128;
static constexpr int M  = Bsz * T;    // 4096
static constexpr int N1 = 3 * Cdim;   // 6144
static constexpr int K1 = Cdim;       // 2048

__device__ __forceinline__ unsigned short f2bf(float f) {
  unsigned u = __float_as_uint(f);
  u += 0x7fffu + ((u >> 16) & 1u);
  return (unsigned short)(u >> 16);
}

__device__ __forceinline__ void gload_lds16(const bf16_t* g, void* l) {
  __builtin_amdgcn_global_load_lds((AS1 const void*)g, (AS3 void*)l, 16, 0, 0);
}

__device__ __forceinline__ float ex2(float x) {
  float r; asm("v_exp_f32 %0, %1" : "=v"(r) : "v"(x)); return r;
}
__device__ __forceinline__ unsigned pk2(float a, float b) {
  unsigned r; asm("v_cvt_pk_bf16_f32 %0, %1, %2" : "=v"(r) : "v"(a), "v"(b)); return r;
}

// ---------------- fp32 -> bf16 elementwise convert (vec4) ----------------
__global__ void cvt_kernel(const float* __restrict__ in, unsigned short* __restrict__ out, int n) {
  int i = (blockIdx.x * blockDim.x + threadIdx.x) * 4;
  if (i >= n) return;
  float4 v = *(const float4*)(in + i);
  ushort4 o;
  o.x = f2bf(v.x); o.y = f2bf(v.y); o.z = f2bf(v.z); o.w = f2bf(v.w);
  *(ushort4*)(out + i) = o;
}

// ---------------- fp32 (KxN) -> bf16 transpose (NxK) ----------------
__global__ void transpose_cvt_kernel(const float* __restrict__ in, unsigned short* __restrict__ out,
                                     int K, int N) {
  __shared__ float tile[32][33];
  int n0 = blockIdx.x * 32, k0 = blockIdx.y * 32;
  int tx = threadIdx.x, ty = threadIdx.y;  // 32 x 8
#pragma unroll
  for (int i = 0; i < 32; i += 8)
    tile[ty + i][tx] = in[(size_t)(k0 + ty + i) * N + n0 + tx];
  __syncthreads();
#pragma unroll
  for (int i = 0; i < 32; i += 8)
    out[(size_t)(n0 + ty + i) * K + k0 + tx] = f2bf(tile[tx][ty + i]);
}

// ---------------- bf16 (T x DH slice of qkv V) -> bf16 Vt[bh][d][t] ----------------
__global__ void vtrans_kernel(const unsigned short* __restrict__ qkv, unsigned short* __restrict__ vt) {
  __shared__ unsigned short tile[32][33];
  int t0 = blockIdx.x * 32, d0 = blockIdx.y * 32, bh = blockIdx.z;
  int b = bh >> 4, h = bh & 15;
  int tx = threadIdx.x, ty = threadIdx.y;  // 32 x 8
  const unsigned short* src = qkv + (size_t)(b * T) * N1 + 2 * Cdim + h * DH;
#pragma unroll
  for (int i = 0; i < 32; i += 8)
    tile[ty + i][tx] = src[(size_t)(t0 + ty + i) * N1 + d0 + tx];
  __syncthreads();
  unsigned short* dst = vt + ((size_t)bh * DH + d0) * T + t0;
#pragma unroll
  for (int i = 0; i < 32; i += 8)
    dst[(size_t)(ty + i) * T + tx] = tile[tx][ty + i];
}

// ---------------- deep-pipelined bf16 GEMM: A (MxK) * BT (NxK) ----------------
// BM=128, BN=256, BK=32. 8 waves (2M x 4N), per-wave 64x64 output.
// Ring-3 LDS (72 KiB -> 2 blocks/CU), prefetch 2 K-tiles ahead, counted
// vmcnt(3), raw s_barrier, setprio around MFMA cluster, XOR-swizzled LDS.
template <int OUT_BF16>
__global__ __launch_bounds__(512, 4) void gemm_p3(const bf16_t* __restrict__ A,
                                                  const bf16_t* __restrict__ BT,
                                                  void* __restrict__ Cp,
                                                  int Nn, int Kk) {
  constexpr int SLOT = 24576;
  __shared__ __align__(16) char ldsmem[3 * SLOT];
  char* ldsb = ldsmem;

  const int tid = threadIdx.x;
  const int wid = tid >> 6, lane = tid & 63;
  const int lq = lane & 15, lk = lane >> 4;
  const int wr = wid >> 2, wc = wid & 3;

  const int nwg = gridDim.x;
  const int bid = blockIdx.x;
  const int q8 = nwg >> 3;
  const int sw = (bid & 7) * q8 + (bid >> 3);
  const int gx = Nn >> 8;
  const int tn = sw % gx;
  const int tm = sw / gx;

  f32x4 acc[4][4] = {};

  int aoff[4], boff[4];
#pragma unroll
  for (int m = 0; m < 4; ++m) {
    int row = wr * 64 + m * 16 + lq;
    aoff[m] = row * 64 + ((lk * 16) ^ (((row >> 1) & 3) << 4));
  }
#pragma unroll
  for (int n = 0; n < 4; ++n) {
    int brow = wc * 64 + n * 16 + lq;
    boff[n] = 8192 + brow * 64 + ((lk * 16) ^ (((brow >> 1) & 3) << 4));
  }

  const int pA = wid * 1024 + lane * 16;
  const int arow = pA >> 6;
  const int acsw = (pA & 63) ^ (((arow >> 1) & 3) << 4);
  const bf16_t* Ags = A + (size_t)(tm * 128 + arow) * Kk + (acsw >> 1);

  const int pB0 = wid * 1024 + lane * 16;
  const int brow0 = pB0 >> 6;
  const int bcsw0 = (pB0 & 63) ^ (((brow0 >> 1) & 3) << 4);
  const bf16_t* Bgs0 = BT + (size_t)(tn * 256 + brow0) * Kk + (bcsw0 >> 1);

  const int pB1 = 8192 + wid * 1024 + lane * 16;
  const int brow1 = pB1 >> 6;  // 128..255
  const int bcsw1 = (pB1 & 63) ^ (((brow1 >> 1) & 3) << 4);
  const bf16_t* Bgs1 = BT + (size_t)(tn * 256 + brow1) * Kk + (bcsw1 >> 1);

  const int ldsA = wid * 1024;
  const int ldsB0 = 8192 + wid * 1024;
  const int ldsB1 = 16384 + wid * 1024;

  auto stage = [&](int kt, int slot) {
    char* db = ldsb + slot * SLOT;
    gload_lds16(Ags + (size_t)kt * 32, db + ldsA);
    gload_lds16(Bgs0 + (size_t)kt * 32, db + ldsB0);
    gload_lds16(Bgs1 + (size_t)kt * 32, db + ldsB1);
  };

  const int nk = Kk >> 5;

  // prologue: stage tiles 0,1; ensure tile 0 landed (tile 1's 3 loads may fly)
  stage(0, 0); stage(1, 1);
  asm volatile("s_waitcnt vmcnt(3)" ::: "memory");
  __builtin_amdgcn_s_barrier();

#define TILE_BODY(KT, SLOT0, SLOT2, STAGE_EN, VM)                                \
  {                                                                              \
    __builtin_amdgcn_sched_barrier(0);                                           \
    const char* sb = ldsb + (SLOT0) * SLOT;                                      \
    bf16x8 af[4], bfv[4];                                                        \
    _Pragma("unroll") for (int m = 0; m < 4; ++m)                                \
      af[m] = *(const bf16x8*)(sb + aoff[m]);                                    \
    _Pragma("unroll") for (int n = 0; n < 4; ++n)                                \
      bfv[n] = *(const bf16x8*)(sb + boff[n]);                                   \
    if (STAGE_EN) stage((KT) + 2, (SLOT2));                                      \
    __builtin_amdgcn_sched_barrier(0);                                           \
    __builtin_amdgcn_s_barrier();                                                \
    asm volatile("s_waitcnt lgkmcnt(0)" ::: "memory");                           \
    __builtin_amdgcn_sched_barrier(0);                                           \
    __builtin_amdgcn_s_setprio(1);                                               \
    _Pragma("unroll") for (int m = 0; m < 4; ++m)                                \
      _Pragma("unroll") for (int n = 0; n < 4; ++n)                              \
        acc[m][n] =                                                              \
            __builtin_amdgcn_mfma_f32_16x16x32_bf16(af[m], bfv[n], acc[m][n], 0, 0, 0); \
    __builtin_amdgcn_s_setprio(0);                                               \
    __builtin_amdgcn_sched_barrier(0);                                           \
    asm volatile("s_waitcnt vmcnt(" #VM ")" ::: "memory");                       \
    __builtin_amdgcn_s_barrier();                                                \
  }

  {
    int c0 = 0;  // slot of tile kt
    for (int kt = 0; kt < nk - 2; ++kt) {
      const int c2 = (c0 >= 1) ? (c0 - 1) : (c0 + 2);  // (c0+2)%3
      TILE_BODY(kt, c0, c2, 1, 3);
      c0 = (c0 >= 2) ? 0 : (c0 + 1);
    }
    TILE_BODY(nk - 2, c0, 0, 0, 0);
    c0 = (c0 >= 2) ? 0 : (c0 + 1);
    TILE_BODY(nk - 1, c0, 0, 0, 0);
  }
#undef TILE_BODY

#pragma unroll
  for (int m = 0; m < 4; ++m)
#pragma unroll
    for (int n = 0; n < 4; ++n)
#pragma unroll
      for (int r = 0; r < 4; ++r) {
        int row = tm * 128 + wr * 64 + m * 16 + lk * 4 + r;
        int col = tn * 256 + wc * 64 + n * 16 + lq;
        if (OUT_BF16)
          ((unsigned short*)Cp)[(size_t)row * Nn + col] = f2bf(acc[m][n][r]);
        else
          ((float*)Cp)[(size_t)row * Nn + col] = acc[m][n][r];
      }
}

// ---------------- causal flash attention: swapped-QK^T 32x32, 8 waves ----------------
// Waves 0-3: q-group g; waves 4-7: q-group 15-g (balanced pairing).
// S^T = mfma(K, Q): q = lane&31 lane-local. O^T = mfma(V^T, P^T). P in registers.
__global__ __launch_bounds__(512, 1) void attn_kernel(const bf16_t* __restrict__ qkv,
                                                      const bf16_t* __restrict__ vt,
                                                      unsigned short* __restrict__ y) {
  __shared__ __align__(16) char lds[65536];  // K dbuf 2x16KB @0, V dbuf 2x16KB @32768
  const int tid = threadIdx.x;
  const int wid = tid >> 6, lane = tid & 63;
  const int l31 = lane & 31, hi = lane >> 5;
  const int hi16 = hi << 4;
  const int bh = blockIdx.x;
  const int g = blockIdx.y;              // pair index 0..7
  const int b = bh >> 4, h = bh & 15;
  const float SC2 = 0.12751879868954096f;  // (1/sqrt(128)) * log2(e)

  const int grp = (wid < 4) ? g : (15 - g);
  const int qlo = grp * 128 + (wid & 3) * 32;
  const int qidx = qlo + l31;
  const int nt = 2 * (15 - g) + 2;        // tiles staged (covers H region)
  const size_t rowbase = (size_t)(b * T) * N1;

  // Q fragments: qf[kk] elem j = Q[qlo+l31][16kk + 8hi + j]
  bf16x8 qf[8];
  {
    const bf16_t* Qg = qkv + rowbase + (size_t)qidx * N1 + h * DH + hi * 8;
#pragma unroll
    for (int kk = 0; kk < 8; ++kk) qf[kk] = *(const bf16x8*)(Qg + kk * 16);
  }

  // staging source pointers (inverse-swizzled global, linear LDS dest)
  const bf16_t* Kg0 = qkv + rowbase + Cdim + h * DH;
  const bf16_t* Vg0 = vt + (size_t)bh * DH * T;
  const int p0 = wid * 1024 + lane * 16;
  const int p1 = 8192 + wid * 1024 + lane * 16;
  const int kr0 = p0 >> 8, kr1 = p1 >> 8;
  const bf16_t* KsA = Kg0 + (size_t)kr0 * N1 + ((((p0 & 255) ^ ((kr0 & 15) << 4))) >> 1);
  const bf16_t* KsB = Kg0 + (size_t)kr1 * N1 + ((((p1 & 255) ^ ((kr1 & 15) << 4))) >> 1);
  const int vr0 = p0 >> 7, vr1 = p1 >> 7;
  const bf16_t* VsA = Vg0 + (size_t)vr0 * T + ((((p0 & 127) ^ ((vr0 & 7) << 4))) >> 1);
  const bf16_t* VsB = Vg0 + (size_t)vr1 * T + ((((p1 & 127) ^ ((vr1 & 7) << 4))) >> 1);
  const int dstoff = wid * 1024;

  auto stage = [&](int tt) {
    char* Kd = lds + (tt & 1) * 16384;
    char* Vd = lds + 32768 + (tt & 1) * 16384;
    const size_t ko = (size_t)(tt * 64) * N1;
    const int vo = tt * 64;
    gload_lds16(KsA + ko, Kd + dstoff);
    gload_lds16(KsB + ko, Kd + 8192 + dstoff);
    gload_lds16(VsA + vo, Vd + dstoff);
    gload_lds16(VsB + vo, Vd + 8192 + dstoff);
  };

  f32x16 oacc[4] = {};
  float mrow = -1e30f, lrow = 0.f;

  stage(0);
  asm volatile("s_waitcnt vmcnt(0)" ::: "memory");
  __builtin_amdgcn_s_barrier();

  for (int t = 0; t < nt; ++t) {
    const int kv0 = t * 64;
    if (t + 1 < nt) stage(t + 1);

    if (kv0 <= qlo + 31) {
      // ---- S^T = K Q^T ----
      f32x16 s0 = {}, s1 = {};
      {
        const char* Kb = lds + (t & 1) * 16384;
        const char* krow0 = Kb + l31 * 256;
        const char* krow1 = Kb + (32 + l31) * 256;
        const int sw0 = (l31 & 15) << 4;
        const int sw1 = ((32 + l31) & 15) << 4;  // == sw0
#pragma unroll
        for (int kk = 0; kk < 8; ++kk) {
          bf16x8 kf0 = *(const bf16x8*)(krow0 + ((kk * 32 + hi16) ^ sw0));
          bf16x8 kf1 = *(const bf16x8*)(krow1 + ((kk * 32 + hi16) ^ sw1));
          s0 = __builtin_amdgcn_mfma_f32_32x32x16_bf16(kf0, qf[kk], s0, 0, 0, 0);
          s1 = __builtin_amdgcn_mfma_f32_32x32x16_bf16(kf1, qf[kk], s1, 0, 0, 0);
        }
      }
      float sv[32];
#pragma unroll
      for (int r = 0; r < 16; ++r) { sv[r] = s0[r]; sv[16 + r] = s1[r]; }
      if (kv0 + 63 > qlo) {  // (partially) diagonal tile: causal mask
#pragma unroll
        for (int r = 0; r < 16; ++r) {
          const int roff = (r & 3) + 8 * (r >> 2);
          if (kv0 + roff + 4 * hi > qidx) sv[r] = -1e30f;
          if (kv0 + 32 + roff + 4 * hi > qidx) sv[16 + r] = -1e30f;
        }
      }
      // ---- online softmax (q lane-local) ----
      float mx = sv[0];
#pragma unroll
      for (int i = 1; i < 32; ++i) mx = fmaxf(mx, sv[i]);
      mx = fmaxf(mx, __shfl_xor(mx, 32));
      const float mn = fmaxf(mrow, mx);
      const float osc = ex2((mrow - mn) * SC2);
      mrow = mn;
      const float mn2 = mn * SC2;
#pragma unroll
      for (int db = 0; db < 4; ++db) oacc[db] *= osc;
      float srow = 0.f;
#pragma unroll
      for (int i = 0; i < 32; ++i) {
        float p = ex2(fmaf(sv[i], SC2, -mn2));
        sv[i] = p;
        srow += p;
      }
      srow += __shfl_xor(srow, 32);
      lrow = lrow * osc + srow;
      // ---- build P^T B-fragments in-register (cvt_pk + lane^32 exchange) ----
      bf16x8 pb[4];
#pragma unroll
      for (int s4 = 0; s4 < 4; ++s4) {
        const int base = (s4 >> 1) * 16 + (s4 & 1) * 8;
        unsigned x0 = pk2(sv[base + 0], sv[base + 1]);
        unsigned x1 = pk2(sv[base + 2], sv[base + 3]);
        unsigned y0 = pk2(sv[base + 4], sv[base + 5]);
        unsigned y1 = pk2(sv[base + 6], sv[base + 7]);
        unsigned e0 = (unsigned)__shfl_xor((int)(hi ? x0 : y0), 32);
        unsigned e1 = (unsigned)__shfl_xor((int)(hi ? x1 : y1), 32);
        union { unsigned u[4]; bf16x8 v; } pbu;
        pbu.u[0] = hi ? e0 : x0;
        pbu.u[1] = hi ? e1 : x1;
        pbu.u[2] = hi ? y0 : e0;
        pbu.u[3] = hi ? y1 : e1;
        pb[s4] = pbu.v;
      }
      // ---- O^T += V^T P^T ----
      {
        const char* Vb = lds + 32768 + (t & 1) * 16384;
#pragma unroll
        for (int db = 0; db < 4; ++db) {
          const int vrow = db * 32 + l31;
          const char* vr = Vb + vrow * 128;
          const int swv = (vrow & 7) << 4;
#pragma unroll
          for (int s4 = 0; s4 < 4; ++s4) {
            bf16x8 vf = *(const bf16x8*)(vr + ((s4 * 32 + hi16) ^ swv));
            oacc[db] = __builtin_amdgcn_mfma_f32_32x32x16_bf16(vf, pb[s4], oacc[db], 0, 0, 0);
          }
        }
      }
    }

    asm volatile("s_waitcnt vmcnt(0)" ::: "memory");
    __builtin_amdgcn_s_barrier();
  }

  // ---- epilogue: O^T[d][q] -> y[q][d] via per-wave LDS transpose ----
  const float inv = 1.0f / lrow;
  char* eb = lds + wid * 8192;  // 32 rows x 256 B, swizzled
#pragma unroll
  for (int db = 0; db < 4; ++db)
#pragma unroll
    for (int r = 0; r < 16; ++r) {
      const int d = db * 32 + (r & 3) + 8 * (r >> 2) + 4 * hi;
      const int off = l31 * 256 + ((d * 2) ^ ((l31 & 15) << 4));
      *(unsigned short*)(eb + off) = f2bf(oacc[db][r] * inv);
    }
  asm volatile("s_waitcnt lgkmcnt(0)" ::: "memory");
  __builtin_amdgcn_sched_barrier(0);
  {
    unsigned short* yr = y + (size_t)(b * T + qlo + l31) * Cdim + h * DH;
#pragma unroll
    for (int rr = 0; rr < 8; ++rr) {
      const int c = hi * 8 + rr;  // 0..15 -> d = c*8 .. c*8+7 (full 128)
      bf16x8 v = *(const bf16x8*)(eb + l31 * 256 + ((c * 16) ^ ((l31 & 15) << 4)));
      *(bf16x8*)(yr + c * 8) = v;
    }
  }
}

extern "C" void kernel_launch(void* const* d_in, const int* in_sizes, int n_in,
                              void* d_out, int out_size, void* d_ws, size_t ws_size,
                              hipStream_t stream) {
  const float* x  = (const float*)d_in[0];
  const float* Wa = (const float*)d_in[1];
  const float* Wp = (const float*)d_in[2];
  float* out = (float*)d_out;
  char* ws = (char*)d_ws;

  size_t o0 = 0;                            // xb : M*K1 bf16 -- reused as Vt after gemm1
  size_t o1 = o0 + (size_t)M * K1 * 2;      // WaT: N1*K1 bf16
  size_t o2 = o1 + (size_t)N1 * K1 * 2;     // qkv: M*N1 bf16
  size_t o3 = o2 + (size_t)M * N1 * 2;      // yb : M*C bf16
  size_t o4 = o3 + (size_t)M * Cdim * 2;    // WpT: C*C bf16

  unsigned short* xb   = (unsigned short*)(ws + o0);
  unsigned short* WaT  = (unsigned short*)(ws + o1);
  unsigned short* qkvb = (unsigned short*)(ws + o2);
  unsigned short* yb   = (unsigned short*)(ws + o3);
  unsigned short* WpT  = (unsigned short*)(ws + o4);
  unsigned short* vtb  = xb;

  cvt_kernel<<<dim3((M * K1 / 4 + 255) / 256), dim3(256), 0, stream>>>(x, xb, M * K1);
  transpose_cvt_kernel<<<dim3(N1 / 32, K1 / 32), dim3(32, 8), 0, stream>>>(Wa, WaT, K1, N1);
  transpose_cvt_kernel<<<dim3(Cdim / 32, Cdim / 32), dim3(32, 8), 0, stream>>>(Wp, WpT, Cdim, Cdim);

  gemm_p3<1><<<dim3((M / 128) * (N1 / 256)), dim3(512), 0, stream>>>(
      (const bf16_t*)xb, (const bf16_t*)WaT, (void*)qkvb, N1, K1);

  vtrans_kernel<<<dim3(T / 32, DH / 32, Bsz * NH), dim3(32, 8), 0, stream>>>(qkvb, vtb);

  attn_kernel<<<dim3(Bsz * NH, 8), dim3(512), 0, stream>>>(
      (const bf16_t*)qkvb, (const bf16_t*)vtb, yb);

  gemm_p3<0><<<dim3((M / 128) * (Cdim / 256)), dim3(512), 0, stream>>>(
      (const bf16_t*)yb, (const bf16_t*)WpT, (void*)out, Cdim, K1);
}

// Round 7
// 241.043 us; speedup vs baseline: 2.4548x; 1.0354x over previous
//
#include <hip/hip_runtime.h>
#include <hip/hip_bf16.h>
#include <stdint.h>

#define AS1 __attribute__((address_space(1)))
#define AS3 __attribute__((address_space(3)))

typedef __bf16 bf16_t;
typedef __bf16 bf16x8 __attribute__((ext_vector_type(8)));
typedef float f32x4 __attribute__((ext_vector_type(4)));
typedef float f32x16 __attribute__((ext_vector_type(16)));

static constexpr int Bsz = 2, T = 2048, Cdim = 2048, NH = 16, DH = 128;
static constexpr int M  = Bsz * T;    // 4096
static constexpr int N1 = 3 * Cdim;   // 6144
static constexpr int K1 = Cdim;       // 2048

__device__ __forceinline__ unsigned short f2bf(float f) {
  unsigned u = __float_as_uint(f);
  u += 0x7fffu + ((u >> 16) & 1u);
  return (unsigned short)(u >> 16);
}

__device__ __forceinline__ void gload_lds16(const bf16_t* g, void* l) {
  __builtin_amdgcn_global_load_lds((AS1 const void*)g, (AS3 void*)l, 16, 0, 0);
}

__device__ __forceinline__ float ex2(float x) {
  float r; asm("v_exp_f32 %0, %1" : "=v"(r) : "v"(x)); return r;
}
__device__ __forceinline__ unsigned pk2(float a, float b) {
  unsigned r; asm("v_cvt_pk_bf16_f32 %0, %1, %2" : "=v"(r) : "v"(a), "v"(b)); return r;
}

// ---------------- fused preamble: cvt(x) + transpose(Wa) + transpose(Wp) ----------------
// blocks [0,8192): cvt x (vec4). [8192,20480): Wa^T. [20480,24576): Wp^T.
__global__ __launch_bounds__(256) void preamble_kernel(const float* __restrict__ x,
                                                       const float* __restrict__ Wa,
                                                       const float* __restrict__ Wp,
                                                       unsigned short* __restrict__ xb,
                                                       unsigned short* __restrict__ WaT,
                                                       unsigned short* __restrict__ WpT) {
  __shared__ float tile[32][33];
  const int blk = blockIdx.x;
  const int tid = threadIdx.x;
  if (blk < 8192) {
    int i = blk * 1024 + tid * 4;
    float4 v = *(const float4*)(x + i);
    ushort4 o;
    o.x = f2bf(v.x); o.y = f2bf(v.y); o.z = f2bf(v.z); o.w = f2bf(v.w);
    *(ushort4*)(xb + i) = o;
    return;
  }
  const float* in;
  unsigned short* out;
  int Nn, bi;
  if (blk < 20480) { in = Wa; out = WaT; Nn = N1;   bi = blk - 8192;  }
  else             { in = Wp; out = WpT; Nn = Cdim; bi = blk - 20480; }
  const int ntiles = Nn >> 5;
  const int n0 = (bi % ntiles) * 32, k0 = (bi / ntiles) * 32;
  const int tx = tid & 31, ty = tid >> 5;  // 32 x 8
#pragma unroll
  for (int i = 0; i < 32; i += 8)
    tile[ty + i][tx] = in[(size_t)(k0 + ty + i) * Nn + n0 + tx];
  __syncthreads();
#pragma unroll
  for (int i = 0; i < 32; i += 8)
    out[(size_t)(n0 + ty + i) * K1 + k0 + tx] = f2bf(tile[tx][ty + i]);
}

// ---------------- deep-pipelined bf16 GEMM: A (MxK) * BT (NxK) ----------------
// BM=128, BN=256, BK=32. 8 waves (2M x 4N), per-wave 64x64 output.
// Ring-3 LDS (72 KiB -> 2 blocks/CU), prefetch 2 K-tiles ahead, counted vmcnt(3),
// raw s_barrier, 2 phases per K-tile (T3-lite role split), XOR-swizzled LDS.
// MODE 0: fp32 out. MODE 1: qkv bf16 out; V-region (tn>=16) written transposed
// into the qkv V stripe remapped as (b*2048+c)*6144 + 4096 + t.
template <int MODE>
__global__ __launch_bounds__(512, 4) void gemm_p3(const bf16_t* __restrict__ A,
                                                  const bf16_t* __restrict__ BT,
                                                  void* __restrict__ Cp,
                                                  int Nn, int Kk) {
  constexpr int SLOT = 24576;
  __shared__ __align__(16) char ldsmem[3 * SLOT];
  char* ldsb = ldsmem;

  const int tid = threadIdx.x;
  const int wid = tid >> 6, lane = tid & 63;
  const int lq = lane & 15, lk = lane >> 4;
  const int wr = wid >> 2, wc = wid & 3;

  const int nwg = gridDim.x;
  const int bid = blockIdx.x;
  const int q8 = nwg >> 3;
  const int sw = (bid & 7) * q8 + (bid >> 3);
  const int gx = Nn >> 8;
  const int tn = sw % gx;
  const int tm = sw / gx;

  f32x4 acc[4][4] = {};

  int aoff[4], boff[4];
#pragma unroll
  for (int m = 0; m < 4; ++m) {
    int row = wr * 64 + m * 16 + lq;
    aoff[m] = row * 64 + ((lk * 16) ^ (((row >> 1) & 3) << 4));
  }
#pragma unroll
  for (int n = 0; n < 4; ++n) {
    int brow = wc * 64 + n * 16 + lq;
    boff[n] = 8192 + brow * 64 + ((lk * 16) ^ (((brow >> 1) & 3) << 4));
  }

  const int pA = wid * 1024 + lane * 16;
  const int arow = pA >> 6;
  const int acsw = (pA & 63) ^ (((arow >> 1) & 3) << 4);
  const bf16_t* Ags = A + (size_t)(tm * 128 + arow) * Kk + (acsw >> 1);

  const int pB0 = wid * 1024 + lane * 16;
  const int brow0 = pB0 >> 6;
  const int bcsw0 = (pB0 & 63) ^ (((brow0 >> 1) & 3) << 4);
  const bf16_t* Bgs0 = BT + (size_t)(tn * 256 + brow0) * Kk + (bcsw0 >> 1);

  const int pB1 = 8192 + wid * 1024 + lane * 16;
  const int brow1 = pB1 >> 6;  // 128..255
  const int bcsw1 = (pB1 & 63) ^ (((brow1 >> 1) & 3) << 4);
  const bf16_t* Bgs1 = BT + (size_t)(tn * 256 + brow1) * Kk + (bcsw1 >> 1);

  const int ldsA = wid * 1024;
  const int ldsB0 = 8192 + wid * 1024;
  const int ldsB1 = 16384 + wid * 1024;

  auto stage = [&](int kt, int slot) {
    char* db = ldsb + slot * SLOT;
    gload_lds16(Ags + (size_t)kt * 32, db + ldsA);
    gload_lds16(Bgs0 + (size_t)kt * 32, db + ldsB0);
    gload_lds16(Bgs1 + (size_t)kt * 32, db + ldsB1);
  };

  const int nk = Kk >> 5;

  // prologue: stage tiles 0,1; ensure tile 0 landed (tile 1's 3 loads may fly)
  stage(0, 0); stage(1, 1);
  asm volatile("s_waitcnt vmcnt(3)" ::: "memory");
  __builtin_amdgcn_s_barrier();

#define TILE_BODY(KT, SLOT0, SLOT2, STAGE_EN, VM)                                \
  {                                                                              \
    __builtin_amdgcn_sched_barrier(0);                                           \
    const char* sb = ldsb + (SLOT0) * SLOT;                                      \
    bf16x8 af0, af1, af2, af3, bfv[4];                                           \
    af0 = *(const bf16x8*)(sb + aoff[0]);                                        \
    af1 = *(const bf16x8*)(sb + aoff[1]);                                        \
    _Pragma("unroll") for (int n = 0; n < 4; ++n)                                \
      bfv[n] = *(const bf16x8*)(sb + boff[n]);                                   \
    if (STAGE_EN) {                                                              \
      char* db = ldsb + (SLOT2) * SLOT;                                          \
      gload_lds16(Ags + (size_t)((KT) + 2) * 32, db + ldsA);                     \
      gload_lds16(Bgs0 + (size_t)((KT) + 2) * 32, db + ldsB0);                   \
    }                                                                            \
    __builtin_amdgcn_sched_barrier(0);                                           \
    __builtin_amdgcn_s_barrier();                                                \
    asm volatile("s_waitcnt lgkmcnt(0)" ::: "memory");                           \
    __builtin_amdgcn_sched_barrier(0);                                           \
    __builtin_amdgcn_s_setprio(1);                                               \
    _Pragma("unroll") for (int n = 0; n < 4; ++n) {                              \
      acc[0][n] = __builtin_amdgcn_mfma_f32_16x16x32_bf16(af0, bfv[n], acc[0][n], 0, 0, 0); \
      acc[1][n] = __builtin_amdgcn_mfma_f32_16x16x32_bf16(af1, bfv[n], acc[1][n], 0, 0, 0); \
    }                                                                            \
    __builtin_amdgcn_s_setprio(0);                                               \
    __builtin_amdgcn_sched_barrier(0);                                           \
    __builtin_amdgcn_s_barrier();                                                \
    af2 = *(const bf16x8*)(sb + aoff[2]);                                        \
    af3 = *(const bf16x8*)(sb + aoff[3]);                                        \
    if (STAGE_EN) {                                                              \
      char* db = ldsb + (SLOT2) * SLOT;                                          \
      gload_lds16(Bgs1 + (size_t)((KT) + 2) * 32, db + ldsB1);                   \
    }                                                                            \
    __builtin_amdgcn_sched_barrier(0);                                           \
    __builtin_amdgcn_s_barrier();                                                \
    asm volatile("s_waitcnt lgkmcnt(0)" ::: "memory");                           \
    __builtin_amdgcn_sched_barrier(0);                                           \
    __builtin_amdgcn_s_setprio(1);                                               \
    _Pragma("unroll") for (int n = 0; n < 4; ++n) {                              \
      acc[2][n] = __builtin_amdgcn_mfma_f32_16x16x32_bf16(af2, bfv[n], acc[2][n], 0, 0, 0); \
      acc[3][n] = __builtin_amdgcn_mfma_f32_16x16x32_bf16(af3, bfv[n], acc[3][n], 0, 0, 0); \
    }                                                                            \
    __builtin_amdgcn_s_setprio(0);                                               \
    __builtin_amdgcn_sched_barrier(0);                                           \
    asm volatile("s_waitcnt vmcnt(" #VM ")" ::: "memory");                       \
    __builtin_amdgcn_s_barrier();                                                \
  }

  {
    int c0 = 0;  // slot of tile kt
    for (int kt = 0; kt < nk - 2; ++kt) {
      const int c2 = (c0 >= 1) ? (c0 - 1) : (c0 + 2);  // (c0+2)%3
      TILE_BODY(kt, c0, c2, 1, 3);
      c0 = (c0 >= 2) ? 0 : (c0 + 1);
    }
    TILE_BODY(nk - 2, c0, 0, 0, 0);
    c0 = (c0 >= 2) ? 0 : (c0 + 1);
    TILE_BODY(nk - 1, c0, 0, 0, 0);
  }
#undef TILE_BODY

  if (MODE == 1 && tn >= 16) {
    // V region: write transposed into qkv V stripe: (b*2048+c)*6144 + 4096 + t
    unsigned short* q16 = (unsigned short*)Cp;
#pragma unroll
    for (int m = 0; m < 4; ++m)
#pragma unroll
      for (int n = 0; n < 4; ++n) {
        int row = tm * 128 + wr * 64 + m * 16 + lk * 4;
        int b_ = row >> 11, t0 = row & 2047;
        int c = tn * 256 - 4096 + wc * 64 + n * 16 + lq;
        ushort4 o;
        o.x = f2bf(acc[m][n][0]); o.y = f2bf(acc[m][n][1]);
        o.z = f2bf(acc[m][n][2]); o.w = f2bf(acc[m][n][3]);
        *(ushort4*)(q16 + (size_t)(b_ * 2048 + c) * N1 + 4096 + t0) = o;
      }
  } else {
#pragma unroll
    for (int m = 0; m < 4; ++m)
#pragma unroll
      for (int n = 0; n < 4; ++n)
#pragma unroll
        for (int r = 0; r < 4; ++r) {
          int row = tm * 128 + wr * 64 + m * 16 + lk * 4 + r;
          int col = tn * 256 + wc * 64 + n * 16 + lq;
          if (MODE == 1)
            ((unsigned short*)Cp)[(size_t)row * Nn + col] = f2bf(acc[m][n][r]);
          else
            ((float*)Cp)[(size_t)row * Nn + col] = acc[m][n][r];
        }
  }
}

// ---------------- causal flash attention: swapped-QK^T 32x32, 8 waves ----------------
// Waves 0-3: q-group g; waves 4-7: q-group 15-g (balanced pairing).
// S^T = mfma(K, Q): q = lane&31 lane-local. O^T = mfma(V^T, P^T). P in registers.
// V read from qkv's remapped V stripe: (b*2048+c)*6144 + 4096 + t (row stride N1).
__global__ __launch_bounds__(512, 1) void attn_kernel(const bf16_t* __restrict__ qkv,
                                                      unsigned short* __restrict__ y) {
  __shared__ __align__(16) char lds[65536];  // K dbuf 2x16KB @0, V dbuf 2x16KB @32768
  const int tid = threadIdx.x;
  const int wid = tid >> 6, lane = tid & 63;
  const int l31 = lane & 31, hi = lane >> 5;
  const int hi16 = hi << 4;
  const int bh = blockIdx.x;
  const int g = blockIdx.y;              // pair index 0..7
  const int b = bh >> 4, h = bh & 15;
  const float SC2 = 0.12751879868954096f;  // (1/sqrt(128)) * log2(e)

  const int grp = (wid < 4) ? g : (15 - g);
  const int qlo = grp * 128 + (wid & 3) * 32;
  const int qidx = qlo + l31;
  const int nt = 2 * (15 - g) + 2;        // tiles staged (covers H region)
  const size_t rowbase = (size_t)(b * T) * N1;

  // Q fragments: qf[kk] elem j = Q[qlo+l31][16kk + 8hi + j]
  bf16x8 qf[8];
  {
    const bf16_t* Qg = qkv + rowbase + (size_t)qidx * N1 + h * DH + hi * 8;
#pragma unroll
    for (int kk = 0; kk < 8; ++kk) qf[kk] = *(const bf16x8*)(Qg + kk * 16);
  }

  // staging source pointers (inverse-swizzled global, linear LDS dest)
  const bf16_t* Kg0 = qkv + rowbase + Cdim + h * DH;
  const bf16_t* Vg0 = qkv + (size_t)(b * 2048 + h * DH) * N1 + 2 * Cdim;
  const int p0 = wid * 1024 + lane * 16;
  const int p1 = 8192 + wid * 1024 + lane * 16;
  const int kr0 = p0 >> 8, kr1 = p1 >> 8;
  const bf16_t* KsA = Kg0 + (size_t)kr0 * N1 + ((((p0 & 255) ^ ((kr0 & 15) << 4))) >> 1);
  const bf16_t* KsB = Kg0 + (size_t)kr1 * N1 + ((((p1 & 255) ^ ((kr1 & 15) << 4))) >> 1);
  const int vr0 = p0 >> 7, vr1 = p1 >> 7;
  const bf16_t* VsA = Vg0 + (size_t)vr0 * N1 + ((((p0 & 127) ^ ((vr0 & 7) << 4))) >> 1);
  const bf16_t* VsB = Vg0 + (size_t)vr1 * N1 + ((((p1 & 127) ^ ((vr1 & 7) << 4))) >> 1);
  const int dstoff = wid * 1024;

  auto stage = [&](int tt) {
    char* Kd = lds + (tt & 1) * 16384;
    char* Vd = lds + 32768 + (tt & 1) * 16384;
    const size_t ko = (size_t)(tt * 64) * N1;
    const int vo = tt * 64;
    gload_lds16(KsA + ko, Kd + dstoff);
    gload_lds16(KsB + ko, Kd + 8192 + dstoff);
    gload_lds16(VsA + vo, Vd + dstoff);
    gload_lds16(VsB + vo, Vd + 8192 + dstoff);
  };

  f32x16 oacc[4] = {};
  float mrow = -1e30f, lrow = 0.f;

  stage(0);
  asm volatile("s_waitcnt vmcnt(0)" ::: "memory");
  __builtin_amdgcn_s_barrier();

  for (int t = 0; t < nt; ++t) {
    const int kv0 = t * 64;
    if (t + 1 < nt) stage(t + 1);

    if (kv0 <= qlo + 31) {
      // ---- S^T = K Q^T ----
      f32x16 s0 = {}, s1 = {};
      {
        const char* Kb = lds + (t & 1) * 16384;
        const char* krow0 = Kb + l31 * 256;
        const char* krow1 = Kb + (32 + l31) * 256;
        const int sw0 = (l31 & 15) << 4;
        const int sw1 = ((32 + l31) & 15) << 4;  // == sw0
#pragma unroll
        for (int kk = 0; kk < 8; ++kk) {
          bf16x8 kf0 = *(const bf16x8*)(krow0 + ((kk * 32 + hi16) ^ sw0));
          bf16x8 kf1 = *(const bf16x8*)(krow1 + ((kk * 32 + hi16) ^ sw1));
          s0 = __builtin_amdgcn_mfma_f32_32x32x16_bf16(kf0, qf[kk], s0, 0, 0, 0);
          s1 = __builtin_amdgcn_mfma_f32_32x32x16_bf16(kf1, qf[kk], s1, 0, 0, 0);
        }
      }
      float sv[32];
#pragma unroll
      for (int r = 0; r < 16; ++r) { sv[r] = s0[r]; sv[16 + r] = s1[r]; }
      if (kv0 + 63 > qlo) {  // (partially) diagonal tile: causal mask
#pragma unroll
        for (int r = 0; r < 16; ++r) {
          const int roff = (r & 3) + 8 * (r >> 2);
          if (kv0 + roff + 4 * hi > qidx) sv[r] = -1e30f;
          if (kv0 + 32 + roff + 4 * hi > qidx) sv[16 + r] = -1e30f;
        }
      }
      // ---- online softmax (q lane-local) ----
      float mx = sv[0];
#pragma unroll
      for (int i = 1; i < 32; ++i) mx = fmaxf(mx, sv[i]);
      mx = fmaxf(mx, __shfl_xor(mx, 32));
      const float mn = fmaxf(mrow, mx);
      const float osc = ex2((mrow - mn) * SC2);
      mrow = mn;
      const float mn2 = mn * SC2;
#pragma unroll
      for (int db = 0; db < 4; ++db) oacc[db] *= osc;
      float srow = 0.f;
#pragma unroll
      for (int i = 0; i < 32; ++i) {
        float p = ex2(fmaf(sv[i], SC2, -mn2));
        sv[i] = p;
        srow += p;
      }
      srow += __shfl_xor(srow, 32);
      lrow = lrow * osc + srow;
      // ---- build P^T B-fragments in-register (cvt_pk + lane^32 exchange) ----
      bf16x8 pb[4];
#pragma unroll
      for (int s4 = 0; s4 < 4; ++s4) {
        const int base = (s4 >> 1) * 16 + (s4 & 1) * 8;
        unsigned x0 = pk2(sv[base + 0], sv[base + 1]);
        unsigned x1 = pk2(sv[base + 2], sv[base + 3]);
        unsigned y0 = pk2(sv[base + 4], sv[base + 5]);
        unsigned y1 = pk2(sv[base + 6], sv[base + 7]);
        unsigned e0 = (unsigned)__shfl_xor((int)(hi ? x0 : y0), 32);
        unsigned e1 = (unsigned)__shfl_xor((int)(hi ? x1 : y1), 32);
        union { unsigned u[4]; bf16x8 v; } pbu;
        pbu.u[0] = hi ? e0 : x0;
        pbu.u[1] = hi ? e1 : x1;
        pbu.u[2] = hi ? y0 : e0;
        pbu.u[3] = hi ? y1 : e1;
        pb[s4] = pbu.v;
      }
      // ---- O^T += V^T P^T ----
      {
        const char* Vb = lds + 32768 + (t & 1) * 16384;
#pragma unroll
        for (int db = 0; db < 4; ++db) {
          const int vrow = db * 32 + l31;
          const char* vr = Vb + vrow * 128;
          const int swv = (vrow & 7) << 4;
#pragma unroll
          for (int s4 = 0; s4 < 4; ++s4) {
            bf16x8 vf = *(const bf16x8*)(vr + ((s4 * 32 + hi16) ^ swv));
            oacc[db] = __builtin_amdgcn_mfma_f32_32x32x16_bf16(vf, pb[s4], oacc[db], 0, 0, 0);
          }
        }
      }
    }

    asm volatile("s_waitcnt vmcnt(0)" ::: "memory");
    __builtin_amdgcn_s_barrier();
  }

  // ---- epilogue: O^T[d][q] -> y[q][d] via per-wave LDS transpose ----
  const float inv = 1.0f / lrow;
  char* eb = lds + wid * 8192;  // 32 rows x 256 B, swizzled
#pragma unroll
  for (int db = 0; db < 4; ++db)
#pragma unroll
    for (int r = 0; r < 16; ++r) {
      const int d = db * 32 + (r & 3) + 8 * (r >> 2) + 4 * hi;
      const int off = l31 * 256 + ((d * 2) ^ ((l31 & 15) << 4));
      *(unsigned short*)(eb + off) = f2bf(oacc[db][r] * inv);
    }
  asm volatile("s_waitcnt lgkmcnt(0)" ::: "memory");
  __builtin_amdgcn_sched_barrier(0);
  {
    unsigned short* yr = y + (size_t)(b * T + qlo + l31) * Cdim + h * DH;
#pragma unroll
    for (int rr = 0; rr < 8; ++rr) {
      const int c = hi * 8 + rr;  // 0..15 -> d = c*8 .. c*8+7 (full 128)
      bf16x8 v = *(const bf16x8*)(eb + l31 * 256 + ((c * 16) ^ ((l31 & 15) << 4)));
      *(bf16x8*)(yr + c * 8) = v;
    }
  }
}

extern "C" void kernel_launch(void* const* d_in, const int* in_sizes, int n_in,
                              void* d_out, int out_size, void* d_ws, size_t ws_size,
                              hipStream_t stream) {
  const float* x  = (const float*)d_in[0];
  const float* Wa = (const float*)d_in[1];
  const float* Wp = (const float*)d_in[2];
  float* out = (float*)d_out;
  char* ws = (char*)d_ws;

  size_t o0 = 0;                            // xb : M*K1 bf16
  size_t o1 = o0 + (size_t)M * K1 * 2;      // WaT: N1*K1 bf16
  size_t o2 = o1 + (size_t)N1 * K1 * 2;     // qkv: M*N1 bf16 (V stripe holds Vt remap)
  size_t o3 = o2 + (size_t)M * N1 * 2;      // yb : M*C bf16
  size_t o4 = o3 + (size_t)M * Cdim * 2;    // WpT: C*C bf16

  unsigned short* xb   = (unsigned short*)(ws + o0);
  unsigned short* WaT  = (unsigned short*)(ws + o1);
  unsigned short* qkvb = (unsigned short*)(ws + o2);
  unsigned short* yb   = (unsigned short*)(ws + o3);
  unsigned short* WpT  = (unsigned short*)(ws + o4);

  preamble_kernel<<<dim3(24576), dim3(256), 0, stream>>>(x, Wa, Wp, xb, WaT, WpT);

  // qkv GEMM: grid = 32*24 = 768 blocks; V-region blocks write Vt directly
  gemm_p3<1><<<dim3((M / 128) * (N1 / 256)), dim3(512), 0, stream>>>(
      (const bf16_t*)xb, (const bf16_t*)WaT, (void*)qkvb, N1, K1);

  attn_kernel<<<dim3(Bsz * NH, 8), dim3(512), 0, stream>>>(
      (const bf16_t*)qkvb, yb);

  // proj GEMM: grid = 32*8 = 256 blocks
  gemm_p3<0><<<dim3((M / 128) * (Cdim / 256)), dim3(512), 0, stream>>>(
      (const bf16_t*)yb, (const bf16_t*)WpT, (void*)out, Cdim, K1);
}

// Round 8
// 232.672 us; speedup vs baseline: 2.5431x; 1.0360x over previous
//
#include <hip/hip_runtime.h>
#include <hip/hip_bf16.h>
#include <stdint.h>

#define AS1 __attribute__((address_space(1)))
#define AS3 __attribute__((address_space(3)))

typedef __bf16 bf16_t;
typedef __bf16 bf16x8 __attribute__((ext_vector_type(8)));
typedef float f32x4 __attribute__((ext_vector_type(4)));
typedef float f32x16 __attribute__((ext_vector_type(16)));

static constexpr int Bsz = 2, T = 2048, Cdim = 2048, NH = 16, DH = 128;
static constexpr int M  = Bsz * T;    // 4096
static constexpr int N1 = 3 * Cdim;   // 6144
static constexpr int K1 = Cdim;       // 2048

__device__ __forceinline__ unsigned short f2bf(float f) {
  unsigned u = __float_as_uint(f);
  u += 0x7fffu + ((u >> 16) & 1u);
  return (unsigned short)(u >> 16);
}

__device__ __forceinline__ void gload_lds16(const bf16_t* g, void* l) {
  __builtin_amdgcn_global_load_lds((AS1 const void*)g, (AS3 void*)l, 16, 0, 0);
}

__device__ __forceinline__ float ex2(float x) {
  float r; asm("v_exp_f32 %0, %1" : "=v"(r) : "v"(x)); return r;
}
__device__ __forceinline__ unsigned pk2(float a, float b) {
  unsigned r; asm("v_cvt_pk_bf16_f32 %0, %1, %2" : "=v"(r) : "v"(a), "v"(b)); return r;
}

// ---------------- fused preamble: cvt(x) + transpose(Wa) + transpose(Wp) ----------------
__global__ __launch_bounds__(256) void preamble_kernel(const float* __restrict__ x,
                                                       const float* __restrict__ Wa,
                                                       const float* __restrict__ Wp,
                                                       unsigned short* __restrict__ xb,
                                                       unsigned short* __restrict__ WaT,
                                                       unsigned short* __restrict__ WpT) {
  __shared__ float tile[32][33];
  const int blk = blockIdx.x;
  const int tid = threadIdx.x;
  if (blk < 8192) {
    int i = blk * 1024 + tid * 4;
    float4 v = *(const float4*)(x + i);
    ushort4 o;
    o.x = f2bf(v.x); o.y = f2bf(v.y); o.z = f2bf(v.z); o.w = f2bf(v.w);
    *(ushort4*)(xb + i) = o;
    return;
  }
  const float* in;
  unsigned short* out;
  int Nn, bi;
  if (blk < 20480) { in = Wa; out = WaT; Nn = N1;   bi = blk - 8192;  }
  else             { in = Wp; out = WpT; Nn = Cdim; bi = blk - 20480; }
  const int ntiles = Nn >> 5;
  const int n0 = (bi % ntiles) * 32, k0 = (bi / ntiles) * 32;
  const int tx = tid & 31, ty = tid >> 5;  // 32 x 8
#pragma unroll
  for (int i = 0; i < 32; i += 8)
    tile[ty + i][tx] = in[(size_t)(k0 + ty + i) * Nn + n0 + tx];
  __syncthreads();
#pragma unroll
  for (int i = 0; i < 32; i += 8)
    out[(size_t)(n0 + ty + i) * K1 + k0 + tx] = f2bf(tile[tx][ty + i]);
}

// ---------------- deep-pipelined bf16 GEMM: A (MxK) * BT (NxK) ----------------
// BM=128, BN=256, BK=32. 8 waves (2M x 4N), per-wave 64x64 output.
// Ring-3 LDS (72 KiB, 2 blocks/CU), prefetch 2 K-tiles ahead, counted vmcnt(3),
// raw s_barrier, setprio around MFMA, XOR-swizzled LDS.
// L2-aware XCD mapping: XCD = bid%8 owns tm in [xcd*4, xcd*4+4), walks tn in
// 8-wide chunks -> per-XCD window: A 2 MB pinned + B 8 MB (vs 24 MB before).
// MODE 0: fp32 out. MODE 1: qkv bf16 out; V-region (tn>=16) written transposed
// into the qkv V stripe remapped as (b*2048+c)*6144 + 4096 + t.
template <int MODE>
__global__ __launch_bounds__(512, 4) void gemm_p3(const bf16_t* __restrict__ A,
                                                  const bf16_t* __restrict__ BT,
                                                  void* __restrict__ Cp,
                                                  int Nn, int Kk) {
  constexpr int SLOT = 24576;
  __shared__ __align__(16) char ldsmem[3 * SLOT];
  char* ldsb = ldsmem;

  const int tid = threadIdx.x;
  const int wid = tid >> 6, lane = tid & 63;
  const int lq = lane & 15, lk = lane >> 4;
  const int wr = wid >> 2, wc = wid & 3;

  // L2-aware XCD mapping (requires gridDim.x % 256 == 0 pattern: gy=32, gx%8==0)
  const int bid = blockIdx.x;
  const int xcd = bid & 7;
  const int j = bid >> 3;
  const int r = j & 31, s5 = j >> 5;
  const int tn = s5 * 8 + (r & 7);
  const int tm = xcd * 4 + (r >> 3);

  f32x4 acc[4][4] = {};

  int aoff[4], boff[4];
#pragma unroll
  for (int m = 0; m < 4; ++m) {
    int row = wr * 64 + m * 16 + lq;
    aoff[m] = row * 64 + ((lk * 16) ^ (((row >> 1) & 3) << 4));
  }
#pragma unroll
  for (int n = 0; n < 4; ++n) {
    int brow = wc * 64 + n * 16 + lq;
    boff[n] = 8192 + brow * 64 + ((lk * 16) ^ (((brow >> 1) & 3) << 4));
  }

  const int pA = wid * 1024 + lane * 16;
  const int arow = pA >> 6;
  const int acsw = (pA & 63) ^ (((arow >> 1) & 3) << 4);
  const bf16_t* Ags = A + (size_t)(tm * 128 + arow) * Kk + (acsw >> 1);

  const int pB0 = wid * 1024 + lane * 16;
  const int brow0 = pB0 >> 6;
  const int bcsw0 = (pB0 & 63) ^ (((brow0 >> 1) & 3) << 4);
  const bf16_t* Bgs0 = BT + (size_t)(tn * 256 + brow0) * Kk + (bcsw0 >> 1);

  const int pB1 = 8192 + wid * 1024 + lane * 16;
  const int brow1 = pB1 >> 6;  // 128..255
  const int bcsw1 = (pB1 & 63) ^ (((brow1 >> 1) & 3) << 4);
  const bf16_t* Bgs1 = BT + (size_t)(tn * 256 + brow1) * Kk + (bcsw1 >> 1);

  const int ldsA = wid * 1024;
  const int ldsB0 = 8192 + wid * 1024;
  const int ldsB1 = 16384 + wid * 1024;

  auto stage = [&](int kt, int slot) {
    char* db = ldsb + slot * SLOT;
    gload_lds16(Ags + (size_t)kt * 32, db + ldsA);
    gload_lds16(Bgs0 + (size_t)kt * 32, db + ldsB0);
    gload_lds16(Bgs1 + (size_t)kt * 32, db + ldsB1);
  };

  const int nk = Kk >> 5;

  stage(0, 0); stage(1, 1);
  asm volatile("s_waitcnt vmcnt(3)" ::: "memory");
  __builtin_amdgcn_s_barrier();

#define TILE_BODY(KT, SLOT0, SLOT2, STAGE_EN, VM)                                \
  {                                                                              \
    __builtin_amdgcn_sched_barrier(0);                                           \
    const char* sb = ldsb + (SLOT0) * SLOT;                                      \
    bf16x8 af[4], bfv[4];                                                        \
    _Pragma("unroll") for (int m = 0; m < 4; ++m)                                \
      af[m] = *(const bf16x8*)(sb + aoff[m]);                                    \
    _Pragma("unroll") for (int n = 0; n < 4; ++n)                                \
      bfv[n] = *(const bf16x8*)(sb + boff[n]);                                   \
    if (STAGE_EN) stage((KT) + 2, (SLOT2));                                      \
    __builtin_amdgcn_sched_barrier(0);                                           \
    __builtin_amdgcn_s_barrier();                                                \
    asm volatile("s_waitcnt lgkmcnt(0)" ::: "memory");                           \
    __builtin_amdgcn_sched_barrier(0);                                           \
    __builtin_amdgcn_s_setprio(1);                                               \
    _Pragma("unroll") for (int m = 0; m < 4; ++m)                                \
      _Pragma("unroll") for (int n = 0; n < 4; ++n)                              \
        acc[m][n] =                                                              \
            __builtin_amdgcn_mfma_f32_16x16x32_bf16(af[m], bfv[n], acc[m][n], 0, 0, 0); \
    __builtin_amdgcn_s_setprio(0);                                               \
    __builtin_amdgcn_sched_barrier(0);                                           \
    asm volatile("s_waitcnt vmcnt(" #VM ")" ::: "memory");                       \
    __builtin_amdgcn_s_barrier();                                                \
  }

  {
    int c0 = 0;  // slot of tile kt
    for (int kt = 0; kt < nk - 2; ++kt) {
      const int c2 = (c0 >= 1) ? (c0 - 1) : (c0 + 2);  // (c0+2)%3
      TILE_BODY(kt, c0, c2, 1, 3);
      c0 = (c0 >= 2) ? 0 : (c0 + 1);
    }
    TILE_BODY(nk - 2, c0, 0, 0, 0);
    c0 = (c0 >= 2) ? 0 : (c0 + 1);
    TILE_BODY(nk - 1, c0, 0, 0, 0);
  }
#undef TILE_BODY

  if (MODE == 1 && tn >= 16) {
    // V region: write transposed into qkv V stripe: (b*2048+c)*6144 + 4096 + t
    unsigned short* q16 = (unsigned short*)Cp;
#pragma unroll
    for (int m = 0; m < 4; ++m)
#pragma unroll
      for (int n = 0; n < 4; ++n) {
        int row = tm * 128 + wr * 64 + m * 16 + lk * 4;
        int b_ = row >> 11, t0 = row & 2047;
        int c = tn * 256 - 4096 + wc * 64 + n * 16 + lq;
        ushort4 o;
        o.x = f2bf(acc[m][n][0]); o.y = f2bf(acc[m][n][1]);
        o.z = f2bf(acc[m][n][2]); o.w = f2bf(acc[m][n][3]);
        *(ushort4*)(q16 + (size_t)(b_ * 2048 + c) * N1 + 4096 + t0) = o;
      }
  } else {
#pragma unroll
    for (int m = 0; m < 4; ++m)
#pragma unroll
      for (int n = 0; n < 4; ++n)
#pragma unroll
        for (int r2 = 0; r2 < 4; ++r2) {
          int row = tm * 128 + wr * 64 + m * 16 + lk * 4 + r2;
          int col = tn * 256 + wc * 64 + n * 16 + lq;
          if (MODE == 1)
            ((unsigned short*)Cp)[(size_t)row * Nn + col] = f2bf(acc[m][n][r2]);
          else
            ((float*)Cp)[(size_t)row * Nn + col] = acc[m][n][r2];
        }
  }
}

// ---------------- causal flash attention: swapped-QK^T 32x32, 8 waves ----------------
// Waves 0-3: q-group g; waves 4-7: q-group 15-g (balanced pairing).
// S^T = mfma(K, Q): q = lane&31 lane-local. O^T = mfma(V^T, P^T). P in registers.
// Ring-3 K/V staging (3 x 32KB), prefetch 2 tiles ahead, counted vmcnt(4).
__global__ __launch_bounds__(512, 1) void attn_kernel(const bf16_t* __restrict__ qkv,
                                                      unsigned short* __restrict__ y) {
  __shared__ __align__(16) char lds[98304];  // 3 slots x (K 16KB + V 16KB)
  const int tid = threadIdx.x;
  const int wid = tid >> 6, lane = tid & 63;
  const int l31 = lane & 31, hi = lane >> 5;
  const int hi16 = hi << 4;
  const int bh = blockIdx.x;
  const int g = blockIdx.y;              // pair index 0..7
  const int b = bh >> 4, h = bh & 15;
  const float SC2 = 0.12751879868954096f;  // (1/sqrt(128)) * log2(e)

  const int grp = (wid < 4) ? g : (15 - g);
  const int qlo = grp * 128 + (wid & 3) * 32;
  const int qidx = qlo + l31;
  const int nt = 2 * (15 - g) + 2;        // tiles staged (>= 18)
  const size_t rowbase = (size_t)(b * T) * N1;

  // Q fragments: qf[kk] elem j = Q[qlo+l31][16kk + 8hi + j]
  bf16x8 qf[8];
  {
    const bf16_t* Qg = qkv + rowbase + (size_t)qidx * N1 + h * DH + hi * 8;
#pragma unroll
    for (int kk = 0; kk < 8; ++kk) qf[kk] = *(const bf16x8*)(Qg + kk * 16);
  }

  // staging source pointers (inverse-swizzled global, linear LDS dest)
  const bf16_t* Kg0 = qkv + rowbase + Cdim + h * DH;
  const bf16_t* Vg0 = qkv + (size_t)(b * 2048 + h * DH) * N1 + 2 * Cdim;
  const int p0 = wid * 1024 + lane * 16;
  const int p1 = 8192 + wid * 1024 + lane * 16;
  const int kr0 = p0 >> 8, kr1 = p1 >> 8;
  const bf16_t* KsA = Kg0 + (size_t)kr0 * N1 + ((((p0 & 255) ^ ((kr0 & 15) << 4))) >> 1);
  const bf16_t* KsB = Kg0 + (size_t)kr1 * N1 + ((((p1 & 255) ^ ((kr1 & 15) << 4))) >> 1);
  const int vr0 = p0 >> 7, vr1 = p1 >> 7;
  const bf16_t* VsA = Vg0 + (size_t)vr0 * N1 + ((((p0 & 127) ^ ((vr0 & 7) << 4))) >> 1);
  const bf16_t* VsB = Vg0 + (size_t)vr1 * N1 + ((((p1 & 127) ^ ((vr1 & 7) << 4))) >> 1);
  const int dstoff = wid * 1024;

  auto stage = [&](int tt, int slot) {
    char* Kd = lds + slot * 32768;
    char* Vd = Kd + 16384;
    const size_t ko = (size_t)(tt * 64) * N1;
    const int vo = tt * 64;
    gload_lds16(KsA + ko, Kd + dstoff);
    gload_lds16(KsB + ko, Kd + 8192 + dstoff);
    gload_lds16(VsA + vo, Vd + dstoff);
    gload_lds16(VsB + vo, Vd + 8192 + dstoff);
  };

  f32x16 oacc[4] = {};
  float mrow = -1e30f, lrow = 0.f;

  // prologue: stage tiles 0,1; wait tile 0 (allow tile 1's 4 loads in flight)
  stage(0, 0); stage(1, 1);
  asm volatile("s_waitcnt vmcnt(4)" ::: "memory");
  __builtin_amdgcn_s_barrier();

  int cs = 0;  // slot of tile t
  for (int t = 0; t < nt; ++t) {
    const int kv0 = t * 64;
    if (t + 2 < nt) {
      const int s2 = (cs >= 1) ? (cs - 1) : (cs + 2);  // (cs+2)%3
      stage(t + 2, s2);
    }

    if (kv0 <= qlo + 31) {
      // ---- S^T = K Q^T ----
      f32x16 s0 = {}, s1 = {};
      {
        const char* Kb = lds + cs * 32768;
        const char* krow0 = Kb + l31 * 256;
        const char* krow1 = Kb + (32 + l31) * 256;
        const int sw0 = (l31 & 15) << 4;
#pragma unroll
        for (int kk = 0; kk < 8; ++kk) {
          bf16x8 kf0 = *(const bf16x8*)(krow0 + ((kk * 32 + hi16) ^ sw0));
          bf16x8 kf1 = *(const bf16x8*)(krow1 + ((kk * 32 + hi16) ^ sw0));
          s0 = __builtin_amdgcn_mfma_f32_32x32x16_bf16(kf0, qf[kk], s0, 0, 0, 0);
          s1 = __builtin_amdgcn_mfma_f32_32x32x16_bf16(kf1, qf[kk], s1, 0, 0, 0);
        }
      }
      float sv[32];
#pragma unroll
      for (int r = 0; r < 16; ++r) { sv[r] = s0[r]; sv[16 + r] = s1[r]; }
      if (kv0 + 63 > qlo) {  // (partially) diagonal tile: causal mask
#pragma unroll
        for (int r = 0; r < 16; ++r) {
          const int roff = (r & 3) + 8 * (r >> 2);
          if (kv0 + roff + 4 * hi > qidx) sv[r] = -1e30f;
          if (kv0 + 32 + roff + 4 * hi > qidx) sv[16 + r] = -1e30f;
        }
      }
      // ---- online softmax (q lane-local) ----
      float mx = sv[0];
#pragma unroll
      for (int i = 1; i < 32; ++i) mx = fmaxf(mx, sv[i]);
      mx = fmaxf(mx, __shfl_xor(mx, 32));
      const float mn = fmaxf(mrow, mx);
      const float osc = ex2((mrow - mn) * SC2);
      mrow = mn;
      const float mn2 = mn * SC2;
#pragma unroll
      for (int db = 0; db < 4; ++db) oacc[db] *= osc;
      float srow = 0.f;
#pragma unroll
      for (int i = 0; i < 32; ++i) {
        float p = ex2(fmaf(sv[i], SC2, -mn2));
        sv[i] = p;
        srow += p;
      }
      srow += __shfl_xor(srow, 32);
      lrow = lrow * osc + srow;
      // ---- build P^T B-fragments in-register (cvt_pk + lane^32 exchange) ----
      bf16x8 pb[4];
#pragma unroll
      for (int s4 = 0; s4 < 4; ++s4) {
        const int base = (s4 >> 1) * 16 + (s4 & 1) * 8;
        unsigned x0 = pk2(sv[base + 0], sv[base + 1]);
        unsigned x1 = pk2(sv[base + 2], sv[base + 3]);
        unsigned y0 = pk2(sv[base + 4], sv[base + 5]);
        unsigned y1 = pk2(sv[base + 6], sv[base + 7]);
        unsigned e0 = (unsigned)__shfl_xor((int)(hi ? x0 : y0), 32);
        unsigned e1 = (unsigned)__shfl_xor((int)(hi ? x1 : y1), 32);
        union { unsigned u[4]; bf16x8 v; } pbu;
        pbu.u[0] = hi ? e0 : x0;
        pbu.u[1] = hi ? e1 : x1;
        pbu.u[2] = hi ? y0 : e0;
        pbu.u[3] = hi ? y1 : e1;
        pb[s4] = pbu.v;
      }
      // ---- O^T += V^T P^T ----
      {
        const char* Vb = lds + cs * 32768 + 16384;
#pragma unroll
        for (int db = 0; db < 4; ++db) {
          const int vrow = db * 32 + l31;
          const char* vr = Vb + vrow * 128;
          const int swv = (vrow & 7) << 4;
#pragma unroll
          for (int s4 = 0; s4 < 4; ++s4) {
            bf16x8 vf = *(const bf16x8*)(vr + ((s4 * 32 + hi16) ^ swv));
            oacc[db] = __builtin_amdgcn_mfma_f32_32x32x16_bf16(vf, pb[s4], oacc[db], 0, 0, 0);
          }
        }
      }
    }

    asm volatile("s_waitcnt vmcnt(4)" ::: "memory");
    __builtin_amdgcn_s_barrier();
    cs = (cs >= 2) ? 0 : (cs + 1);
  }

  // ---- epilogue: O^T[d][q] -> y[q][d] via per-wave LDS transpose ----
  const float inv = 1.0f / lrow;
  char* eb = lds + wid * 8192;  // 32 rows x 256 B, swizzled (per-wave private)
#pragma unroll
  for (int db = 0; db < 4; ++db)
#pragma unroll
    for (int r = 0; r < 16; ++r) {
      const int d = db * 32 + (r & 3) + 8 * (r >> 2) + 4 * hi;
      const int off = l31 * 256 + ((d * 2) ^ ((l31 & 15) << 4));
      *(unsigned short*)(eb + off) = f2bf(oacc[db][r] * inv);
    }
  asm volatile("s_waitcnt lgkmcnt(0)" ::: "memory");
  __builtin_amdgcn_sched_barrier(0);
  {
    unsigned short* yr = y + (size_t)(b * T + qlo + l31) * Cdim + h * DH;
#pragma unroll
    for (int rr = 0; rr < 8; ++rr) {
      const int c = hi * 8 + rr;  // 0..15 -> d = c*8 .. c*8+7 (full 128)
      bf16x8 v = *(const bf16x8*)(eb + l31 * 256 + ((c * 16) ^ ((l31 & 15) << 4)));
      *(bf16x8*)(yr + c * 8) = v;
    }
  }
}

extern "C" void kernel_launch(void* const* d_in, const int* in_sizes, int n_in,
                              void* d_out, int out_size, void* d_ws, size_t ws_size,
                              hipStream_t stream) {
  const float* x  = (const float*)d_in[0];
  const float* Wa = (const float*)d_in[1];
  const float* Wp = (const float*)d_in[2];
  float* out = (float*)d_out;
  char* ws = (char*)d_ws;

  size_t o0 = 0;                            // xb : M*K1 bf16
  size_t o1 = o0 + (size_t)M * K1 * 2;      // WaT: N1*K1 bf16
  size_t o2 = o1 + (size_t)N1 * K1 * 2;     // qkv: M*N1 bf16 (V stripe holds Vt remap)
  size_t o3 = o2 + (size_t)M * N1 * 2;      // yb : M*C bf16
  size_t o4 = o3 + (size_t)M * Cdim * 2;    // WpT: C*C bf16

  unsigned short* xb   = (unsigned short*)(ws + o0);
  unsigned short* WaT  = (unsigned short*)(ws + o1);
  unsigned short* qkvb = (unsigned short*)(ws + o2);
  unsigned short* yb   = (unsigned short*)(ws + o3);
  unsigned short* WpT  = (unsigned short*)(ws + o4);

  preamble_kernel<<<dim3(24576), dim3(256), 0, stream>>>(x, Wa, Wp, xb, WaT, WpT);

  // qkv GEMM: grid = 32*24 = 768 blocks; V-region blocks write Vt directly
  gemm_p3<1><<<dim3((M / 128) * (N1 / 256)), dim3(512), 0, stream>>>(
      (const bf16_t*)xb, (const bf16_t*)WaT, (void*)qkvb, N1, K1);

  attn_kernel<<<dim3(Bsz * NH, 8), dim3(512), 0, stream>>>(
      (const bf16_t*)qkvb, yb);

  // proj GEMM: grid = 32*8 = 256 blocks
  gemm_p3<0><<<dim3((M / 128) * (Cdim / 256)), dim3(512), 0, stream>>>(
      (const bf16_t*)yb, (const bf16_t*)WpT, (void*)out, Cdim, K1);
}